// Round 17
// baseline (522.838 us; speedup 1.0000x reference)
//
#include <hip/hip_runtime.h>
#include <stdint.h>

typedef unsigned short u16;
typedef unsigned int u32;
typedef __attribute__((ext_vector_type(4))) float f32x4;
typedef __attribute__((ext_vector_type(8))) short bf16x8;

#define NB 128      // graphs
#define LL 256      // nodes per graph
#define DD 128      // hidden
#define EDGES 524288
#define EPG 4096    // edges per graph
#define NN (NB*LL)

__device__ __forceinline__ float bf2f(u16 u) {
    union { u32 i; float f; } v; v.i = ((u32)u) << 16; return v.f;
}
__device__ __forceinline__ u16 f2bf(float f) {
    union { float f; u32 i; } v; v.f = f;
    u32 i = v.i;
    u32 r = (i + 0x7fffu + ((i >> 16) & 1u)) >> 16;   // RNE
    return (u16)r;
}
__device__ __forceinline__ float matfn(float a, float dv) {
    if (a != 0.f) return (a == 1.2f) ? 1.1f : a;
    return (dv == 0.f) ? 0.f : exp2f((1.f - dv) * 0.5849625007211562f); // 1.5^(1-dis)
}
__device__ __forceinline__ float red16(float v) {
#pragma unroll
    for (int off = 1; off < 16; off <<= 1) v += __shfl_xor(v, off, 64);
    return v;
}
__device__ __forceinline__ u32 cvtpk(float lo, float hi) {
    u32 r;
    asm("v_cvt_pk_bf16_f32 %0, %1, %2" : "=v"(r) : "v"(lo), "v"(hi));
    return r;
}
__device__ __forceinline__ u32 bperm(int srcLane, u32 v) {
    return (u32)__builtin_amdgcn_ds_bpermute(srcLane << 2, (int)v);
}

// ---------------- prep kernels ----------------

// zero the 32 MiB Wf region with float4 stores
__global__ __launch_bounds__(256) void zero_wf_k(float4* __restrict__ p) {
    p[blockIdx.x * 256 + threadIdx.x] = make_float4(0.f, 0.f, 0.f, 0.f);
}

__global__ __launch_bounds__(256) void scatter_w_k(const int* __restrict__ srcI,
                                                   const int* __restrict__ dstI,
                                                   const float* __restrict__ ew,
                                                   float* __restrict__ Wf) {
    int e = blockIdx.x * 256 + threadIdx.x;
    if (e >= EDGES) return;
    int b = e >> 12;
    atomicAdd(&Wf[(size_t)b * 65536 + (size_t)(dstI[e] & 255) * 256 + (srcI[e] & 255)], ew[e]);
}

// NOTE: must run BEFORE build_matrix_k (matB aliases Wf).
__global__ __launch_bounds__(256) void cast_w_k(const float* __restrict__ Wf, u16* __restrict__ Wb) {
    int i = blockIdx.x * 256 + threadIdx.x;
    float4 v = ((const float4*)Wf)[i];
    ushort4 o;
    o.x = f2bf(v.x); o.y = f2bf(v.y); o.z = f2bf(v.z); o.w = f2bf(v.w);
    ((ushort4*)Wb)[i] = o;
}

// matB holds bf16(0.125 * matfn) (attn scale folded in)
__global__ __launch_bounds__(256) void build_matrix_k(const float* __restrict__ adj,
                                                      const float* __restrict__ dis,
                                                      u16* __restrict__ matB) {
    int i = blockIdx.x * 256 + threadIdx.x;
    matB[i] = f2bf(0.125f * matfn(adj[i], dis[i]));
}

// all weight transposes in one kernel (655360 elements, 2560 blocks)
__global__ __launch_bounds__(256) void prep_weights_k(
        const float* __restrict__ g0_rel_w, const float* __restrict__ g0_root_w,
        const float* __restrict__ g_rel_w,  const float* __restrict__ g_root_w,
        const float* __restrict__ wq, const float* __restrict__ wk,
        const float* __restrict__ wv, const float* __restrict__ fc,
        const float* __restrict__ proj_w,
        u16* __restrict__ wconvT0, u16* __restrict__ wconvT,
        u16* __restrict__ wqkvT, u16* __restrict__ fcT, u16* __restrict__ projT) {
    int i = blockIdx.x * 256 + threadIdx.x;
    if (i < 16384) {
        int m = i >> 7, k = i & 127;
        float v = 0.f;
        if (k < 40) v = g0_rel_w[k * 128 + m];
        else if (k >= 64 && k < 104) v = g0_root_w[(k - 64) * 128 + m];
        wconvT0[i] = f2bf(v);
        return;
    }
    i -= 16384;
    if (i < 98304) {
        int l = i >> 15, jj = i & 32767;
        int m = jj >> 8, k = jj & 255;
        float v = (k < 128) ? g_rel_w[l * 16384 + k * 128 + m]
                            : g_root_w[l * 16384 + (k - 128) * 128 + m];
        wconvT[i] = f2bf(v);
        return;
    }
    i -= 98304;
    if (i < 393216) {
        int l = i / 98304, jj = i % 98304;
        int m = jj >> 7, k = jj & 127;
        const float* s = (m < 256) ? wq : (m < 512) ? wk : wv;
        int mm = m & 255;
        wqkvT[i] = f2bf(s[l * 32768 + k * 256 + mm]);
        return;
    }
    i -= 393216;
    if (i < 131072) {
        int l = i >> 15, jj = i & 32767;
        int m = jj >> 8, k = jj & 255;
        fcT[i] = f2bf(fc[l * 32768 + k * 128 + m]);
        return;
    }
    i -= 131072;
    {
        int m = i >> 7, k = i & 127;
        projT[i] = f2bf(proj_w[k * 128 + m]);
    }
}

// layer-0 transpose: x [N,40] f32 (zero-padded to 128) -> hT [b][128][256]
__global__ __launch_bounds__(256) void transpose_x_k(const float* __restrict__ x,
                                                     u16* __restrict__ hT) {
    int gw = blockIdx.x * 4 + (threadIdx.x >> 6);
    int lane = threadIdx.x & 63;
    int b = gw >> 6, rem = gw & 63, db = rem >> 5, jb = rem & 31;
    int d = (db << 6) + lane;
    u16 vals[8];
#pragma unroll
    for (int jj = 0; jj < 8; ++jj) {
        int node = (b << 8) + (jb << 3) + jj;
        vals[jj] = (d < 40) ? f2bf(x[(size_t)node * 40 + d]) : (u16)0;
    }
    *(uint4*)(hT + (size_t)b * 32768 + (size_t)d * 256 + (jb << 3)) = *(uint4*)vals;
}

// ---------------- FUSED per-graph agg GEMM + conv GEMM + bias+LN+relu ----------------

template<bool IS0>
__global__ __launch_bounds__(256) void gemm_agg_conv(const u16* __restrict__ Wb,
                                                     const u16* __restrict__ BT0,
                                                     const float* __restrict__ x,
                                                     u16* h,
                                                     const u16* __restrict__ BTc,
                                                     const float* __restrict__ rb,
                                                     const float* __restrict__ g,
                                                     const float* __restrict__ be) {
    __shared__ __align__(16) u16 lds[8192 + 128 * 136];   // 16KB stage + 34816B aggT
    char* ldsc = (char*)lds;
    u16* aggT = lds + 8192;
    int t = threadIdx.x, lane = t & 63, wid = t >> 6;
    int b = blockIdx.x >> 1, rt = blockIdx.x & 1;
    int row0 = rt << 7, nbase = b << 8;
    const u16* A = Wb + (size_t)b * 65536 + (size_t)row0 * 256;
    const u16* BT = BT0 + (size_t)b * 32768;

    f32x4 zero = {0.f, 0.f, 0.f, 0.f};
    f32x4 acc[4][4];
#pragma unroll
    for (int mt = 0; mt < 4; ++mt)
#pragma unroll
        for (int nt = 0; nt < 4; ++nt) acc[mt][nt] = zero;

    int wr = wid >> 1, wc = wid & 1;
    int rA = wr * 64 + (lane & 15);
    int rB = wc * 64 + (lane & 15);
    int kch = (lane >> 4) << 4;

    // ---- Phase A: agg GEMM ----
    for (int kt = 0; kt < 8; ++kt) {
        int kc = kt << 5;
#pragma unroll
        for (int i = 0; i < 2; ++i) {
            int off = wid * 2048 + i * 1024 + lane * 16;
            int r = off >> 6, cb = off & 63;
            __builtin_amdgcn_global_load_lds((const u32*)((const char*)A + ((size_t)r * 256 + kc) * 2 + cb),
                                             (u32*)(ldsc + wid * 2048 + i * 1024), 16, 0, 0);
            __builtin_amdgcn_global_load_lds((const u32*)((const char*)BT + ((size_t)r * 256 + kc) * 2 + cb),
                                             (u32*)(ldsc + 8192 + wid * 2048 + i * 1024), 16, 0, 0);
        }
        __syncthreads();
        bf16x8 af[4], bfr[4];
#pragma unroll
        for (int mt = 0; mt < 4; ++mt)
            af[mt] = *(const bf16x8*)(ldsc + (rA + mt * 16) * 64 + kch);
#pragma unroll
        for (int nt = 0; nt < 4; ++nt)
            bfr[nt] = *(const bf16x8*)(ldsc + 8192 + (rB + nt * 16) * 64 + kch);
#pragma unroll
        for (int mt = 0; mt < 4; ++mt)
#pragma unroll
            for (int nt = 0; nt < 4; ++nt)
                acc[mt][nt] = __builtin_amdgcn_mfma_f32_16x16x32_bf16(af[mt], bfr[nt], acc[mt][nt], 0, 0, 0);
        __syncthreads();
    }

    // ---- Phase B: acc -> aggT ----
    {
        int colb = wc * 64 + (lane & 15);
        int rowb = wr * 64 + ((lane >> 4) << 2);
#pragma unroll
        for (int mt = 0; mt < 4; ++mt)
#pragma unroll
            for (int nt = 0; nt < 4; ++nt)
#pragma unroll
                for (int r = 0; r < 4; ++r)
                    aggT[(rowb + mt * 16 + r) * 136 + colb + nt * 16] = f2bf(acc[mt][nt][r]);
        if (IS0) {
            for (int idx = t; idx < 128 * 40; idx += 256) {
                int i = idx / 40, c = idx - i * 40;
                aggT[i * 136 + 64 + c] = f2bf(x[(size_t)(nbase + row0 + i) * 40 + c]);
            }
        }
    }
    __syncthreads();

    // ---- Phase C: conv GEMM ----
#pragma unroll
    for (int mt = 0; mt < 4; ++mt)
#pragma unroll
        for (int nt = 0; nt < 4; ++nt) acc[mt][nt] = zero;

    const int NKT = IS0 ? 4 : 8;
    const int KK = IS0 ? 128 : 256;
    for (int kt = 0; kt < NKT; ++kt) {
        int kc = kt << 5;
        bool fromLds = IS0 || (kt < 4);
#pragma unroll
        for (int i = 0; i < 2; ++i) {
            int off = wid * 2048 + i * 1024 + lane * 16;
            int r = off >> 6, cb = off & 63;
            if (!fromLds) {
                int kcl = (kt - 4) << 5;
                __builtin_amdgcn_global_load_lds((const u32*)((const char*)h + ((size_t)(nbase + row0 + r) * 128 + kcl) * 2 + cb),
                                                 (u32*)(ldsc + wid * 2048 + i * 1024), 16, 0, 0);
            }
            __builtin_amdgcn_global_load_lds((const u32*)((const char*)BTc + ((size_t)r * KK + kc) * 2 + cb),
                                             (u32*)(ldsc + 8192 + wid * 2048 + i * 1024), 16, 0, 0);
        }
        __syncthreads();
        bf16x8 af[4], bfr[4];
        if (fromLds) {
#pragma unroll
            for (int mt = 0; mt < 4; ++mt)
                af[mt] = *(const bf16x8*)((const char*)aggT + (rA + mt * 16) * 272 + kt * 64 + kch);
        } else {
#pragma unroll
            for (int mt = 0; mt < 4; ++mt)
                af[mt] = *(const bf16x8*)(ldsc + (rA + mt * 16) * 64 + kch);
        }
#pragma unroll
        for (int nt = 0; nt < 4; ++nt)
            bfr[nt] = *(const bf16x8*)(ldsc + 8192 + (rB + nt * 16) * 64 + kch);
#pragma unroll
        for (int mt = 0; mt < 4; ++mt)
#pragma unroll
            for (int nt = 0; nt < 4; ++nt)
                acc[mt][nt] = __builtin_amdgcn_mfma_f32_16x16x32_bf16(af[mt], bfr[nt], acc[mt][nt], 0, 0, 0);
        __syncthreads();
    }

    // ---- Phase D: bias + LN + relu -> h ----
    float* redS = (float*)ldsc;
    float* redQ = (float*)(ldsc + 2048);
    int colbase = wc * 64 + (lane & 15);
    int qrow = (lane >> 4) << 2;
    float rbv[4], gv[4], bev[4];
#pragma unroll
    for (int nt = 0; nt < 4; ++nt) {
        int c = colbase + nt * 16;
        rbv[nt] = rb[c]; gv[nt] = g[c]; bev[nt] = be[c];
    }
#pragma unroll
    for (int mt = 0; mt < 4; ++mt)
#pragma unroll
        for (int r = 0; r < 4; ++r) {
            float s = 0.f, q = 0.f;
#pragma unroll
            for (int nt = 0; nt < 4; ++nt) {
                float v = acc[mt][nt][r] + rbv[nt];
                s += v; q += v * v;
            }
            s = red16(s); q = red16(q);
            if ((lane & 15) == 0) {
                int lr = wr * 64 + qrow + mt * 16 + r;
                redS[lr * 2 + wc] = s; redQ[lr * 2 + wc] = q;
            }
        }
    __syncthreads();
#pragma unroll
    for (int mt = 0; mt < 4; ++mt)
#pragma unroll
        for (int r = 0; r < 4; ++r) {
            int lr = wr * 64 + qrow + mt * 16 + r;
            float mu = (redS[lr * 2] + redS[lr * 2 + 1]) * (1.f / 128.f);
            float var = (redQ[lr * 2] + redQ[lr * 2 + 1]) * (1.f / 128.f) - mu * mu;
            float rs = rsqrtf(var + 1e-5f);
            size_t rbase = (size_t)(nbase + row0 + lr) * 128;
#pragma unroll
            for (int nt = 0; nt < 4; ++nt) {
                float v = acc[mt][nt][r] + rbv[nt];
                float o = (v - mu) * rs * gv[nt] + bev[nt];
                o = o < 0.f ? 0.f : o;
                h[rbase + colbase + nt * 16] = f2bf(o);
            }
        }
}

// ---------------- qkv GEMM (K=128, Mtot=768): Q,K -> packed [bh][256][64]; V -> vT [bh][64][256] ----------------

__global__ __launch_bounds__(256) void gemm_qkv(const u16* __restrict__ A,
                                                const u16* __restrict__ BT,
                                                u16* __restrict__ qP,
                                                u16* __restrict__ kP,
                                                u16* __restrict__ vT) {
    __shared__ __align__(16) u16 lds[8192];
    char* ldsc = (char*)lds;
    int t = threadIdx.x, lane = t & 63, wid = t >> 6;
    int row0 = blockIdx.x * 128, col0 = blockIdx.y * 128;

    f32x4 zero = {0.f, 0.f, 0.f, 0.f};
    f32x4 acc[4][4];
#pragma unroll
    for (int mt = 0; mt < 4; ++mt)
#pragma unroll
        for (int nt = 0; nt < 4; ++nt) acc[mt][nt] = zero;

    int wr = wid >> 1, wc = wid & 1;
    int rA = wr * 64 + (lane & 15);
    int rB = wc * 64 + (lane & 15);
    int kch = (lane >> 4) << 4;

    for (int kt = 0; kt < 4; ++kt) {
        int kc = kt << 5;
#pragma unroll
        for (int i = 0; i < 2; ++i) {
            int off = wid * 2048 + i * 1024 + lane * 16;
            int r = off >> 6, cb = off & 63;
            __builtin_amdgcn_global_load_lds((const u32*)((const char*)A + ((size_t)(row0 + r) * 128 + kc) * 2 + cb),
                                             (u32*)(ldsc + wid * 2048 + i * 1024), 16, 0, 0);
            __builtin_amdgcn_global_load_lds((const u32*)((const char*)BT + ((size_t)(col0 + r) * 128 + kc) * 2 + cb),
                                             (u32*)(ldsc + 8192 + wid * 2048 + i * 1024), 16, 0, 0);
        }
        __syncthreads();
        bf16x8 af[4], bfr[4];
#pragma unroll
        for (int mt = 0; mt < 4; ++mt)
            af[mt] = *(const bf16x8*)(ldsc + (rA + mt * 16) * 64 + kch);
#pragma unroll
        for (int nt = 0; nt < 4; ++nt)
            bfr[nt] = *(const bf16x8*)(ldsc + 8192 + (rB + nt * 16) * 64 + kch);
#pragma unroll
        for (int mt = 0; mt < 4; ++mt)
#pragma unroll
            for (int nt = 0; nt < 4; ++nt)
                acc[mt][nt] = __builtin_amdgcn_mfma_f32_16x16x32_bf16(af[mt], bfr[nt], acc[mt][nt], 0, 0, 0);
        __syncthreads();
    }

    int colb = col0 + wc * 64 + (lane & 15);
    int rowb = row0 + wr * 64 + ((lane >> 4) << 2);
    int bb = row0 >> 8;
    if (col0 < 512) {
        u16* dst = (col0 < 256) ? qP : kP;
#pragma unroll
        for (int mt = 0; mt < 4; ++mt) {
#pragma unroll
            for (int nt = 0; nt < 4; ++nt) {
                int c = (colb + nt * 16) & 255;
                int hh = c >> 6, d = c & 63;
#pragma unroll
                for (int r = 0; r < 4; ++r) {
                    int node = (rowb + mt * 16 + r) & 255;
                    dst[(size_t)(bb * 4 + hh) * 16384 + node * 64 + d] = f2bf(acc[mt][nt][r]);
                }
            }
        }
    } else {
#pragma unroll
        for (int mt = 0; mt < 4; ++mt) {
            int node0 = (rowb + mt * 16) & 255;
#pragma unroll
            for (int nt = 0; nt < 4; ++nt) {
                int c = colb + nt * 16 - 512;
                int hh = c >> 6, d = c & 63;
                u16 tmp[4];
#pragma unroll
                for (int r = 0; r < 4; ++r) tmp[r] = f2bf(acc[mt][nt][r]);
                *(ushort4*)(vT + (size_t)(bb * 4 + hh) * 16384 + d * 256 + node0) = *(ushort4*)tmp;
            }
        }
    }
}

// ---------------- final projection GEMM (K=128, f32 out + bias) ----------------

__global__ __launch_bounds__(256) void gemm_proj(const u16* __restrict__ A,
                                                 const u16* __restrict__ BT,
                                                 float* __restrict__ Out,
                                                 const float* __restrict__ bias) {
    __shared__ __align__(16) u16 lds[8192];
    char* ldsc = (char*)lds;
    int t = threadIdx.x, lane = t & 63, wid = t >> 6;
    int row0 = blockIdx.x * 128;

    f32x4 zero = {0.f, 0.f, 0.f, 0.f};
    f32x4 acc[4][4];
#pragma unroll
    for (int mt = 0; mt < 4; ++mt)
#pragma unroll
        for (int nt = 0; nt < 4; ++nt) acc[mt][nt] = zero;

    int wr = wid >> 1, wc = wid & 1;
    int rA = wr * 64 + (lane & 15);
    int rB = wc * 64 + (lane & 15);
    int kch = (lane >> 4) << 4;

    for (int kt = 0; kt < 4; ++kt) {
        int kc = kt << 5;
#pragma unroll
        for (int i = 0; i < 2; ++i) {
            int off = wid * 2048 + i * 1024 + lane * 16;
            int r = off >> 6, cb = off & 63;
            __builtin_amdgcn_global_load_lds((const u32*)((const char*)A + ((size_t)(row0 + r) * 128 + kc) * 2 + cb),
                                             (u32*)(ldsc + wid * 2048 + i * 1024), 16, 0, 0);
            __builtin_amdgcn_global_load_lds((const u32*)((const char*)BT + ((size_t)r * 128 + kc) * 2 + cb),
                                             (u32*)(ldsc + 8192 + wid * 2048 + i * 1024), 16, 0, 0);
        }
        __syncthreads();
        bf16x8 af[4], bfr[4];
#pragma unroll
        for (int mt = 0; mt < 4; ++mt)
            af[mt] = *(const bf16x8*)(ldsc + (rA + mt * 16) * 64 + kch);
#pragma unroll
        for (int nt = 0; nt < 4; ++nt)
            bfr[nt] = *(const bf16x8*)(ldsc + 8192 + (rB + nt * 16) * 64 + kch);
#pragma unroll
        for (int mt = 0; mt < 4; ++mt)
#pragma unroll
            for (int nt = 0; nt < 4; ++nt)
                acc[mt][nt] = __builtin_amdgcn_mfma_f32_16x16x32_bf16(af[mt], bfr[nt], acc[mt][nt], 0, 0, 0);
        __syncthreads();
    }

    int colb = wc * 64 + (lane & 15);
    int rowb = row0 + wr * 64 + ((lane >> 4) << 2);
#pragma unroll
    for (int mt = 0; mt < 4; ++mt)
#pragma unroll
        for (int nt = 0; nt < 4; ++nt)
#pragma unroll
            for (int r = 0; r < 4; ++r)
                Out[(size_t)(rowb + mt * 16 + r) * 128 + colb + nt * 16] =
                    acc[mt][nt][r] + bias[colb + nt * 16];
}

// ---------------- fc GEMM: fused LN -> +residual -> LN; writes h AND hT (for next layer's agg) ----------------

__global__ __launch_bounds__(256) void gemm_fc_ln2(const u16* __restrict__ A,
                                                   const u16* __restrict__ BT,
                                                   const float* __restrict__ mg,
                                                   const float* __restrict__ mb,
                                                   const float* __restrict__ eg,
                                                   const float* __restrict__ eb,
                                                   u16* __restrict__ h,
                                                   u16* __restrict__ hT) {
    __shared__ __align__(16) u16 lds[8192];
    char* ldsc = (char*)lds;
    int t = threadIdx.x, lane = t & 63, wid = t >> 6;
    int row0 = blockIdx.x * 128;

    f32x4 zero = {0.f, 0.f, 0.f, 0.f};
    f32x4 acc[4][4];
#pragma unroll
    for (int mt = 0; mt < 4; ++mt)
#pragma unroll
        for (int nt = 0; nt < 4; ++nt) acc[mt][nt] = zero;

    int wr = wid >> 1, wc = wid & 1;
    int rA = wr * 64 + (lane & 15);
    int rB = wc * 64 + (lane & 15);
    int kch = (lane >> 4) << 4;

    for (int kt = 0; kt < 8; ++kt) {
        int kc = kt << 5;
#pragma unroll
        for (int i = 0; i < 2; ++i) {
            int off = wid * 2048 + i * 1024 + lane * 16;
            int r = off >> 6, cb = off & 63;
            __builtin_amdgcn_global_load_lds((const u32*)((const char*)A + ((size_t)(row0 + r) * 256 + kc) * 2 + cb),
                                             (u32*)(ldsc + wid * 2048 + i * 1024), 16, 0, 0);
            __builtin_amdgcn_global_load_lds((const u32*)((const char*)BT + ((size_t)r * 256 + kc) * 2 + cb),
                                             (u32*)(ldsc + 8192 + wid * 2048 + i * 1024), 16, 0, 0);
        }
        __syncthreads();
        bf16x8 af[4], bfr[4];
#pragma unroll
        for (int mt = 0; mt < 4; ++mt)
            af[mt] = *(const bf16x8*)(ldsc + (rA + mt * 16) * 64 + kch);
#pragma unroll
        for (int nt = 0; nt < 4; ++nt)
            bfr[nt] = *(const bf16x8*)(ldsc + 8192 + (rB + nt * 16) * 64 + kch);
#pragma unroll
        for (int mt = 0; mt < 4; ++mt)
#pragma unroll
            for (int nt = 0; nt < 4; ++nt)
                acc[mt][nt] = __builtin_amdgcn_mfma_f32_16x16x32_bf16(af[mt], bfr[nt], acc[mt][nt], 0, 0, 0);
        __syncthreads();
    }

    float* redS  = (float*)ldsc;
    float* redQ  = (float*)(ldsc + 2048);
    float* redS2 = (float*)(ldsc + 4096);
    float* redQ2 = (float*)(ldsc + 6144);
    int colbase = wc * 64 + (lane & 15);
    int qrow = (lane >> 4) << 2;
    float mgv[4], mbv[4], egv[4], ebv[4];
#pragma unroll
    for (int nt = 0; nt < 4; ++nt) {
        int c = colbase + nt * 16;
        mgv[nt] = mg[c]; mbv[nt] = mb[c]; egv[nt] = eg[c]; ebv[nt] = eb[c];
    }
#pragma unroll
    for (int mt = 0; mt < 4; ++mt)
#pragma unroll
        for (int r = 0; r < 4; ++r) {
            float s = 0.f, q = 0.f;
#pragma unroll
            for (int nt = 0; nt < 4; ++nt) {
                float v = acc[mt][nt][r];
                s += v; q += v * v;
            }
            s = red16(s); q = red16(q);
            if ((lane & 15) == 0) {
                int lr = wr * 64 + qrow + mt * 16 + r;
                redS[lr * 2 + wc] = s; redQ[lr * 2 + wc] = q;
            }
        }
    __syncthreads();
#pragma unroll
    for (int mt = 0; mt < 4; ++mt)
#pragma unroll
        for (int r = 0; r < 4; ++r) {
            int lr = wr * 64 + qrow + mt * 16 + r;
            float mu = (redS[lr * 2] + redS[lr * 2 + 1]) * (1.f / 128.f);
            float var = (redQ[lr * 2] + redQ[lr * 2 + 1]) * (1.f / 128.f) - mu * mu;
            float rs = rsqrtf(var + 1e-5f);
            size_t rbase = (size_t)(row0 + lr) * 128;
            float s2 = 0.f, q2 = 0.f;
#pragma unroll
            for (int nt = 0; nt < 4; ++nt) {
                float o = (acc[mt][nt][r] - mu) * rs * mgv[nt] + mbv[nt];
                float z = o + bf2f(h[rbase + colbase + nt * 16]);
                acc[mt][nt][r] = z;
                s2 += z; q2 += z * z;
            }
            s2 = red16(s2); q2 = red16(q2);
            if ((lane & 15) == 0) {
                redS2[lr * 2 + wc] = s2; redQ2[lr * 2 + wc] = q2;
            }
        }
    __syncthreads();
    int bb = row0 >> 8;
#pragma unroll
    for (int mt = 0; mt < 4; ++mt) {
        u16 tvals[4][4];   // [nt][r]
#pragma unroll
        for (int r = 0; r < 4; ++r) {
            int lr = wr * 64 + qrow + mt * 16 + r;
            float mu = (redS2[lr * 2] + redS2[lr * 2 + 1]) * (1.f / 128.f);
            float var = (redQ2[lr * 2] + redQ2[lr * 2 + 1]) * (1.f / 128.f) - mu * mu;
            float rs = rsqrtf(var + 1e-5f);
            size_t rbase = (size_t)(row0 + lr) * 128;
#pragma unroll
            for (int nt = 0; nt < 4; ++nt) {
                float z = acc[mt][nt][r];
                u16 o = f2bf((z - mu) * rs * egv[nt] + ebv[nt]);
                h[rbase + colbase + nt * 16] = o;
                tvals[nt][r] = o;
            }
        }
        int node0 = ((row0 & 255) + wr * 64 + qrow + mt * 16);
#pragma unroll
        for (int nt = 0; nt < 4; ++nt) {
            int d = colbase + nt * 16;
            *(ushort4*)(hT + (size_t)bb * 32768 + (size_t)d * 256 + node0) = *(ushort4*)tvals[nt];
        }
    }
}

// ---------------- fused attention: T14 V-reg split; per (b, head, qhalf) block ----------------
// grid (NB, 4, 2). V global loads issued up-front into regs; K staged to LDS; after softmax
// V regs -> LDS -> PV.

__global__ __launch_bounds__(512) void attn_k(const u16* __restrict__ qP,
                                              const u16* __restrict__ kP,
                                              const u16* __restrict__ vT,
                                              const u16* __restrict__ matB,
                                              u16* __restrict__ ctx) {
    __shared__ __align__(16) u16 Kl[256 * 72];   // 36864 B (padded rows)
    __shared__ __align__(16) u16 Vl[64 * 264];   // 33792 B (padded rows)
    int t = threadIdx.x, lane = t & 63, w = t >> 6;
    int b = blockIdx.x, hh = blockIdx.y, zh = blockIdx.z;
    int bh = b * 4 + hh;
    int lg = lane >> 4, q16 = lane & 15;
    int qrow_l = zh * 128 + w * 16;

    // Q fragments + V chunks: issue global loads FIRST (independent of LDS)
    const u16* qsrc = qP + (size_t)bh * 16384 + (qrow_l + q16) * 64 + (lg << 3);
    bf16x8 aq0 = *(const bf16x8*)(qsrc);
    bf16x8 aq1 = *(const bf16x8*)(qsrc + 32);

    const u16* vb = vT + (size_t)bh * 16384;
    uint4 vreg[4];
#pragma unroll
    for (int i = 0; i < 4; ++i) {
        int idx = i * 512 + t;              // 2048 x 16B; V row = 256 u16 = 32 chunks
        int d = idx >> 5, p = idx & 31;
        vreg[i] = *(const uint4*)(vb + d * 256 + p * 8);
    }

    // K staged to LDS (first barrier waits only on K)
    {
        const u16* kb = kP + (size_t)bh * 16384;
#pragma unroll
        for (int i = 0; i < 4; ++i) {
            int idx = i * 512 + t;              // 2048 x 16B; K row = 64 u16 = 8 chunks
            int node = idx >> 3, oct = idx & 7;
            *(uint4*)(Kl + node * 72 + oct * 8) = *(const uint4*)(kb + node * 64 + oct * 8);
        }
    }
    __syncthreads();

    f32x4 zero = {0.f, 0.f, 0.f, 0.f};
    bool loA = (lg < 2);
    int s01 = q16 + ((lg & 1) << 5);
    int s23 = s01 + 16;

    f32x4 sc[16];
    __builtin_amdgcn_s_setprio(1);
#pragma unroll
    for (int nt = 0; nt < 16; ++nt) {
        const u16* ks = Kl + (nt * 16 + q16) * 72 + (lg << 3);
        bf16x8 k0 = *(const bf16x8*)(ks);
        bf16x8 k1 = *(const bf16x8*)(ks + 32);
        f32x4 a = __builtin_amdgcn_mfma_f32_16x16x32_bf16(k0, aq0, zero, 0, 0, 0);
        a = __builtin_amdgcn_mfma_f32_16x16x32_bf16(k1, aq1, a, 0, 0, 0);
        sc[nt] = a;
    }
    __builtin_amdgcn_s_setprio(0);

    const u16* mrow = matB + ((size_t)b * LL + qrow_l + q16) * LL + (lg << 2);
#pragma unroll
    for (int nt = 0; nt < 16; ++nt) {
        ushort4 mv = *(const ushort4*)(mrow + nt * 16);
        sc[nt][0] *= bf2f(mv.x);
        sc[nt][1] *= bf2f(mv.y);
        sc[nt][2] *= bf2f(mv.z);
        sc[nt][3] *= bf2f(mv.w);
    }

    float mx = -1e30f;
#pragma unroll
    for (int nt = 0; nt < 16; ++nt)
#pragma unroll
        for (int r = 0; r < 4; ++r) mx = fmaxf(mx, sc[nt][r]);
    mx = fmaxf(mx, __shfl_xor(mx, 16, 64));
    mx = fmaxf(mx, __shfl_xor(mx, 32, 64));
    float sm = 0.f;
#pragma unroll
    for (int nt = 0; nt < 16; ++nt)
#pragma unroll
        for (int r = 0; r < 4; ++r) {
            float e = __expf(sc[nt][r] - mx);
            sc[nt][r] = e;
            sm += e;
        }
    sm += __shfl_xor(sm, 16, 64);
    sm += __shfl_xor(sm, 32, 64);
    float inv = 1.f / sm;
#pragma unroll
    for (int nt = 0; nt < 16; ++nt)
#pragma unroll
        for (int r = 0; r < 4; ++r) sc[nt][r] *= inv;

    // write V regs to LDS now that softmax is done
#pragma unroll
    for (int i = 0; i < 4; ++i) {
        int idx = i * 512 + t;
        int d = idx >> 5, p = idx & 31;
        *(uint4*)(Vl + d * 264 + p * 8) = vreg[i];
    }
    __syncthreads();

    f32x4 oa[4];
#pragma unroll
    for (int dt = 0; dt < 4; ++dt) oa[dt] = zero;
    __builtin_amdgcn_s_setprio(1);
#pragma unroll
    for (int kt = 0; kt < 8; ++kt) {
        u32 A0 = cvtpk(sc[2 * kt][0], sc[2 * kt][1]);
        u32 A1 = cvtpk(sc[2 * kt][2], sc[2 * kt][3]);
        u32 B0 = cvtpk(sc[2 * kt + 1][0], sc[2 * kt + 1][1]);
        u32 B1 = cvtpk(sc[2 * kt + 1][2], sc[2 * kt + 1][3]);
        u32 a0s = bperm(s01, A0), b0s = bperm(s01, B0);
        u32 a1s = bperm(s01, A1), b1s = bperm(s01, B1);
        u32 a0t = bperm(s23, A0), b0t = bperm(s23, B0);
        u32 a1t = bperm(s23, A1), b1t = bperm(s23, B1);
        union { u32 u[4]; bf16x8 v; } pa;
        pa.u[0] = loA ? a0s : b0s;
        pa.u[1] = loA ? a1s : b1s;
        pa.u[2] = loA ? a0t : b0t;
        pa.u[3] = loA ? a1t : b1t;
#pragma unroll
        for (int dt = 0; dt < 4; ++dt) {
            bf16x8 bv = *(const bf16x8*)(Vl + (dt * 16 + q16) * 264 + kt * 32 + (lg << 3));
            oa[dt] = __builtin_amdgcn_mfma_f32_16x16x32_bf16(pa.v, bv, oa[dt], 0, 0, 0);
        }
    }
    __builtin_amdgcn_s_setprio(0);
#pragma unroll
    for (int dt = 0; dt < 4; ++dt)
#pragma unroll
        for (int r = 0; r < 4; ++r)
            ctx[(size_t)(b * LL + qrow_l + (lg << 2) + r) * 256 + hh * 64 + dt * 16 + q16] = f2bf(oa[dt][r]);
}

// ---------------- host launch ----------------

extern "C" void kernel_launch(void* const* d_in, const int* in_sizes, int n_in,
                              void* d_out, int out_size, void* d_ws, size_t ws_size,
                              hipStream_t stream) {
    (void)out_size; (void)ws_size; (void)n_in;
    const float* x        = (const float*)d_in[0];
    const int*   ei       = (const int*)d_in[1];
    const float* ea       = (const float*)d_in[2];
    const float* adj      = (const float*)d_in[3];
    const float* dis      = (const float*)d_in[4];
    int pb = (in_sizes[5] == 5120) ? 5 : 6;
    const float* g0_rel_w = (const float*)d_in[pb + 0];
    const float* g0_rel_b = (const float*)d_in[pb + 1];
    const float* g0_root_w= (const float*)d_in[pb + 2];
    const float* g_rel_w  = (const float*)d_in[pb + 3];
    const float* g_rel_b  = (const float*)d_in[pb + 4];
    const float* g_root_w = (const float*)d_in[pb + 5];
    const float* nm_g     = (const float*)d_in[pb + 6];
    const float* nm_b     = (const float*)d_in[pb + 7];
    const float* wq       = (const float*)d_in[pb + 8];
    const float* wk       = (const float*)d_in[pb + 9];
    const float* wv       = (const float*)d_in[pb + 10];
    const float* fc       = (const float*)d_in[pb + 11];
    const float* mha_g    = (const float*)d_in[pb + 12];
    const float* mha_b    = (const float*)d_in[pb + 13];
    const float* enc_g    = (const float*)d_in[pb + 14];
    const float* enc_b    = (const float*)d_in[pb + 15];
    const float* proj_w   = (const float*)d_in[pb + 16];
    const float* proj_b   = (const float*)d_in[pb + 17];
    const int* srcI = ei;
    const int* dstI = ei + EDGES;

    char* w = (char*)d_ws;
    float* Wf     = (float*)w; w += (size_t)33554432;   // W f32 scatter, then reused as matB (bf16)
    u16*   ctx    = (u16*)w;   w += (size_t)16777216;   // attn output [N,256]
    u16*   h      = (u16*)w;   w += (size_t)8388608;
    u16*   qP     = (u16*)w;   w += (size_t)16777216;   // packed Q [bh][256][64]
    u16*   kP     = (u16*)w;   w += (size_t)16777216;   // packed K [bh][256][64]
    u16*   Wb     = (u16*)w;   w += (size_t)16777216;   // W bf16 [128][256][256]
    u16*   bigT   = (u16*)w;   w += (size_t)16777216;   // hT (8.4MB) / vT (16.7MB), time-disjoint
    u16* wconvT0  = (u16*)w;   w += (size_t)32768;
    u16* wconvT   = (u16*)w;   w += (size_t)196608;
    u16* wqkvT    = (u16*)w;   w += (size_t)786432;
    u16* fcT      = (u16*)w;   w += (size_t)262144;
    u16* projT    = (u16*)w;   w += (size_t)32768;
    u16*   matB = (u16*)Wf;
    u16*   hT  = bigT;
    u16*   vT  = bigT;

    // --- prep (cast MUST precede build_matrix: matB aliases Wf) ---
    zero_wf_k<<<8192, 256, 0, stream>>>((float4*)Wf);
    scatter_w_k<<<2048, 256, 0, stream>>>(srcI, dstI, ea, Wf);
    cast_w_k<<<8192, 256, 0, stream>>>(Wf, Wb);
    build_matrix_k<<<32768, 256, 0, stream>>>(adj, dis, matB);
    prep_weights_k<<<2560, 256, 0, stream>>>(g0_rel_w, g0_root_w, g_rel_w, g_root_w,
                                             wq, wk, wv, fc, proj_w,
                                             wconvT0, wconvT, wqkvT, fcT, projT);
    transpose_x_k<<<2048, 256, 0, stream>>>(x, hT);

    for (int L = 0; L < 4; ++L) {
        if (L == 0)
            gemm_agg_conv<true><<<256, 256, 0, stream>>>(Wb, hT, x, h, wconvT0,
                                                         g0_rel_b, nm_g, nm_b);
        else
            gemm_agg_conv<false><<<256, 256, 0, stream>>>(Wb, hT, x, h, wconvT + (L - 1) * 32768,
                                                          g_rel_b + (L - 1) * 128,
                                                          nm_g + L * 128, nm_b + L * 128);
        gemm_qkv<<<dim3(256, 6), 256, 0, stream>>>(h, wqkvT + L * 98304, qP, kP, vT);
        attn_k<<<dim3(NB, 4, 2), 512, 0, stream>>>(qP, kP, vT, matB, ctx);
        gemm_fc_ln2<<<256, 256, 0, stream>>>(ctx, fcT + L * 32768,
                                             mha_g + L * 128, mha_b + L * 128,
                                             enc_g + L * 128, enc_b + L * 128, h, hT);
    }
    gemm_proj<<<256, 256, 0, stream>>>(h, projT, (float*)d_out, proj_b);
}

// Round 18
// 473.166 us; speedup vs baseline: 1.1050x; 1.1050x over previous
//
#include <hip/hip_runtime.h>
#include <stdint.h>

typedef unsigned short u16;
typedef unsigned int u32;
typedef __attribute__((ext_vector_type(4))) float f32x4;
typedef __attribute__((ext_vector_type(8))) short bf16x8;

#define NB 128      // graphs
#define LL 256      // nodes per graph
#define DD 128      // hidden
#define EDGES 524288
#define EPG 4096    // edges per graph
#define NN (NB*LL)

__device__ __forceinline__ float bf2f(u16 u) {
    union { u32 i; float f; } v; v.i = ((u32)u) << 16; return v.f;
}
__device__ __forceinline__ u16 f2bf(float f) {
    union { float f; u32 i; } v; v.f = f;
    u32 i = v.i;
    u32 r = (i + 0x7fffu + ((i >> 16) & 1u)) >> 16;   // RNE
    return (u16)r;
}
__device__ __forceinline__ float matfn(float a, float dv) {
    if (a != 0.f) return (a == 1.2f) ? 1.1f : a;
    return (dv == 0.f) ? 0.f : exp2f((1.f - dv) * 0.5849625007211562f); // 1.5^(1-dis)
}
__device__ __forceinline__ float red16(float v) {
#pragma unroll
    for (int off = 1; off < 16; off <<= 1) v += __shfl_xor(v, off, 64);
    return v;
}
__device__ __forceinline__ u32 cvtpk(float lo, float hi) {
    u32 r;
    asm("v_cvt_pk_bf16_f32 %0, %1, %2" : "=v"(r) : "v"(lo), "v"(hi));
    return r;
}
__device__ __forceinline__ u32 bperm(int srcLane, u32 v) {
    return (u32)__builtin_amdgcn_ds_bpermute(srcLane << 2, (int)v);
}

// ---------------- prep kernels ----------------

// zero the 32 MiB Wf region with float4 stores
__global__ __launch_bounds__(256) void zero_wf_k(float4* __restrict__ p) {
    p[blockIdx.x * 256 + threadIdx.x] = make_float4(0.f, 0.f, 0.f, 0.f);
}

__global__ __launch_bounds__(256) void scatter_w_k(const int* __restrict__ srcI,
                                                   const int* __restrict__ dstI,
                                                   const float* __restrict__ ew,
                                                   float* __restrict__ Wf) {
    int e = blockIdx.x * 256 + threadIdx.x;
    if (e >= EDGES) return;
    int b = e >> 12;
    atomicAdd(&Wf[(size_t)b * 65536 + (size_t)(dstI[e] & 255) * 256 + (srcI[e] & 255)], ew[e]);
}

// NOTE: must run BEFORE build_matrix_k (matB aliases Wf).
__global__ __launch_bounds__(256) void cast_w_k(const float* __restrict__ Wf, u16* __restrict__ Wb) {
    int i = blockIdx.x * 256 + threadIdx.x;
    float4 v = ((const float4*)Wf)[i];
    ushort4 o;
    o.x = f2bf(v.x); o.y = f2bf(v.y); o.z = f2bf(v.z); o.w = f2bf(v.w);
    ((ushort4*)Wb)[i] = o;
}

// matB holds bf16(0.125 * matfn) (attn scale folded in)
__global__ __launch_bounds__(256) void build_matrix_k(const float* __restrict__ adj,
                                                      const float* __restrict__ dis,
                                                      u16* __restrict__ matB) {
    int i = blockIdx.x * 256 + threadIdx.x;
    matB[i] = f2bf(0.125f * matfn(adj[i], dis[i]));
}

// all weight transposes in one kernel (655360 elements, 2560 blocks)
__global__ __launch_bounds__(256) void prep_weights_k(
        const float* __restrict__ g0_rel_w, const float* __restrict__ g0_root_w,
        const float* __restrict__ g_rel_w,  const float* __restrict__ g_root_w,
        const float* __restrict__ wq, const float* __restrict__ wk,
        const float* __restrict__ wv, const float* __restrict__ fc,
        const float* __restrict__ proj_w,
        u16* __restrict__ wconvT0, u16* __restrict__ wconvT,
        u16* __restrict__ wqkvT, u16* __restrict__ fcT, u16* __restrict__ projT) {
    int i = blockIdx.x * 256 + threadIdx.x;
    if (i < 16384) {
        int m = i >> 7, k = i & 127;
        float v = 0.f;
        if (k < 40) v = g0_rel_w[k * 128 + m];
        else if (k >= 64 && k < 104) v = g0_root_w[(k - 64) * 128 + m];
        wconvT0[i] = f2bf(v);
        return;
    }
    i -= 16384;
    if (i < 98304) {
        int l = i >> 15, jj = i & 32767;
        int m = jj >> 8, k = jj & 255;
        float v = (k < 128) ? g_rel_w[l * 16384 + k * 128 + m]
                            : g_root_w[l * 16384 + (k - 128) * 128 + m];
        wconvT[i] = f2bf(v);
        return;
    }
    i -= 98304;
    if (i < 393216) {
        int l = i / 98304, jj = i % 98304;
        int m = jj >> 7, k = jj & 127;
        const float* s = (m < 256) ? wq : (m < 512) ? wk : wv;
        int mm = m & 255;
        wqkvT[i] = f2bf(s[l * 32768 + k * 256 + mm]);
        return;
    }
    i -= 393216;
    if (i < 131072) {
        int l = i >> 15, jj = i & 32767;
        int m = jj >> 8, k = jj & 255;
        fcT[i] = f2bf(fc[l * 32768 + k * 128 + m]);
        return;
    }
    i -= 131072;
    {
        int m = i >> 7, k = i & 127;
        projT[i] = f2bf(proj_w[k * 128 + m]);
    }
}

// layer-0 transpose: x [N,40] f32 (zero-padded to 128) -> hT [b][128][256]
__global__ __launch_bounds__(256) void transpose_x_k(const float* __restrict__ x,
                                                     u16* __restrict__ hT) {
    int gw = blockIdx.x * 4 + (threadIdx.x >> 6);
    int lane = threadIdx.x & 63;
    int b = gw >> 6, rem = gw & 63, db = rem >> 5, jb = rem & 31;
    int d = (db << 6) + lane;
    u16 vals[8];
#pragma unroll
    for (int jj = 0; jj < 8; ++jj) {
        int node = (b << 8) + (jb << 3) + jj;
        vals[jj] = (d < 40) ? f2bf(x[(size_t)node * 40 + d]) : (u16)0;
    }
    *(uint4*)(hT + (size_t)b * 32768 + (size_t)d * 256 + (jb << 3)) = *(uint4*)vals;
}

// ---------------- FUSED per-graph agg GEMM + conv GEMM + bias+LN+relu ----------------

template<bool IS0>
__global__ __launch_bounds__(256) void gemm_agg_conv(const u16* __restrict__ Wb,
                                                     const u16* __restrict__ BT0,
                                                     const float* __restrict__ x,
                                                     u16* h,
                                                     const u16* __restrict__ BTc,
                                                     const float* __restrict__ rb,
                                                     const float* __restrict__ g,
                                                     const float* __restrict__ be) {
    __shared__ __align__(16) u16 lds[8192 + 128 * 136];   // 16KB stage + 34816B aggT
    char* ldsc = (char*)lds;
    u16* aggT = lds + 8192;
    int t = threadIdx.x, lane = t & 63, wid = t >> 6;
    int b = blockIdx.x >> 1, rt = blockIdx.x & 1;
    int row0 = rt << 7, nbase = b << 8;
    const u16* A = Wb + (size_t)b * 65536 + (size_t)row0 * 256;
    const u16* BT = BT0 + (size_t)b * 32768;

    f32x4 zero = {0.f, 0.f, 0.f, 0.f};
    f32x4 acc[4][4];
#pragma unroll
    for (int mt = 0; mt < 4; ++mt)
#pragma unroll
        for (int nt = 0; nt < 4; ++nt) acc[mt][nt] = zero;

    int wr = wid >> 1, wc = wid & 1;
    int rA = wr * 64 + (lane & 15);
    int rB = wc * 64 + (lane & 15);
    int kch = (lane >> 4) << 4;

    // ---- Phase A: agg GEMM ----
    for (int kt = 0; kt < 8; ++kt) {
        int kc = kt << 5;
#pragma unroll
        for (int i = 0; i < 2; ++i) {
            int off = wid * 2048 + i * 1024 + lane * 16;
            int r = off >> 6, cb = off & 63;
            __builtin_amdgcn_global_load_lds((const u32*)((const char*)A + ((size_t)r * 256 + kc) * 2 + cb),
                                             (u32*)(ldsc + wid * 2048 + i * 1024), 16, 0, 0);
            __builtin_amdgcn_global_load_lds((const u32*)((const char*)BT + ((size_t)r * 256 + kc) * 2 + cb),
                                             (u32*)(ldsc + 8192 + wid * 2048 + i * 1024), 16, 0, 0);
        }
        __syncthreads();
        bf16x8 af[4], bfr[4];
#pragma unroll
        for (int mt = 0; mt < 4; ++mt)
            af[mt] = *(const bf16x8*)(ldsc + (rA + mt * 16) * 64 + kch);
#pragma unroll
        for (int nt = 0; nt < 4; ++nt)
            bfr[nt] = *(const bf16x8*)(ldsc + 8192 + (rB + nt * 16) * 64 + kch);
#pragma unroll
        for (int mt = 0; mt < 4; ++mt)
#pragma unroll
            for (int nt = 0; nt < 4; ++nt)
                acc[mt][nt] = __builtin_amdgcn_mfma_f32_16x16x32_bf16(af[mt], bfr[nt], acc[mt][nt], 0, 0, 0);
        __syncthreads();
    }

    // ---- Phase B: acc -> aggT ----
    {
        int colb = wc * 64 + (lane & 15);
        int rowb = wr * 64 + ((lane >> 4) << 2);
#pragma unroll
        for (int mt = 0; mt < 4; ++mt)
#pragma unroll
            for (int nt = 0; nt < 4; ++nt)
#pragma unroll
                for (int r = 0; r < 4; ++r)
                    aggT[(rowb + mt * 16 + r) * 136 + colb + nt * 16] = f2bf(acc[mt][nt][r]);
        if (IS0) {
            for (int idx = t; idx < 128 * 40; idx += 256) {
                int i = idx / 40, c = idx - i * 40;
                aggT[i * 136 + 64 + c] = f2bf(x[(size_t)(nbase + row0 + i) * 40 + c]);
            }
        }
    }
    __syncthreads();

    // ---- Phase C: conv GEMM ----
#pragma unroll
    for (int mt = 0; mt < 4; ++mt)
#pragma unroll
        for (int nt = 0; nt < 4; ++nt) acc[mt][nt] = zero;

    const int NKT = IS0 ? 4 : 8;
    const int KK = IS0 ? 128 : 256;
    for (int kt = 0; kt < NKT; ++kt) {
        int kc = kt << 5;
        bool fromLds = IS0 || (kt < 4);
#pragma unroll
        for (int i = 0; i < 2; ++i) {
            int off = wid * 2048 + i * 1024 + lane * 16;
            int r = off >> 6, cb = off & 63;
            if (!fromLds) {
                int kcl = (kt - 4) << 5;
                __builtin_amdgcn_global_load_lds((const u32*)((const char*)h + ((size_t)(nbase + row0 + r) * 128 + kcl) * 2 + cb),
                                                 (u32*)(ldsc + wid * 2048 + i * 1024), 16, 0, 0);
            }
            __builtin_amdgcn_global_load_lds((const u32*)((const char*)BTc + ((size_t)r * KK + kc) * 2 + cb),
                                             (u32*)(ldsc + 8192 + wid * 2048 + i * 1024), 16, 0, 0);
        }
        __syncthreads();
        bf16x8 af[4], bfr[4];
        if (fromLds) {
#pragma unroll
            for (int mt = 0; mt < 4; ++mt)
                af[mt] = *(const bf16x8*)((const char*)aggT + (rA + mt * 16) * 272 + kt * 64 + kch);
        } else {
#pragma unroll
            for (int mt = 0; mt < 4; ++mt)
                af[mt] = *(const bf16x8*)(ldsc + (rA + mt * 16) * 64 + kch);
        }
#pragma unroll
        for (int nt = 0; nt < 4; ++nt)
            bfr[nt] = *(const bf16x8*)(ldsc + 8192 + (rB + nt * 16) * 64 + kch);
#pragma unroll
        for (int mt = 0; mt < 4; ++mt)
#pragma unroll
            for (int nt = 0; nt < 4; ++nt)
                acc[mt][nt] = __builtin_amdgcn_mfma_f32_16x16x32_bf16(af[mt], bfr[nt], acc[mt][nt], 0, 0, 0);
        __syncthreads();
    }

    // ---- Phase D: bias + LN + relu -> h ----
    float* redS = (float*)ldsc;
    float* redQ = (float*)(ldsc + 2048);
    int colbase = wc * 64 + (lane & 15);
    int qrow = (lane >> 4) << 2;
    float rbv[4], gv[4], bev[4];
#pragma unroll
    for (int nt = 0; nt < 4; ++nt) {
        int c = colbase + nt * 16;
        rbv[nt] = rb[c]; gv[nt] = g[c]; bev[nt] = be[c];
    }
#pragma unroll
    for (int mt = 0; mt < 4; ++mt)
#pragma unroll
        for (int r = 0; r < 4; ++r) {
            float s = 0.f, q = 0.f;
#pragma unroll
            for (int nt = 0; nt < 4; ++nt) {
                float v = acc[mt][nt][r] + rbv[nt];
                s += v; q += v * v;
            }
            s = red16(s); q = red16(q);
            if ((lane & 15) == 0) {
                int lr = wr * 64 + qrow + mt * 16 + r;
                redS[lr * 2 + wc] = s; redQ[lr * 2 + wc] = q;
            }
        }
    __syncthreads();
#pragma unroll
    for (int mt = 0; mt < 4; ++mt)
#pragma unroll
        for (int r = 0; r < 4; ++r) {
            int lr = wr * 64 + qrow + mt * 16 + r;
            float mu = (redS[lr * 2] + redS[lr * 2 + 1]) * (1.f / 128.f);
            float var = (redQ[lr * 2] + redQ[lr * 2 + 1]) * (1.f / 128.f) - mu * mu;
            float rs = rsqrtf(var + 1e-5f);
            size_t rbase = (size_t)(nbase + row0 + lr) * 128;
#pragma unroll
            for (int nt = 0; nt < 4; ++nt) {
                float v = acc[mt][nt][r] + rbv[nt];
                float o = (v - mu) * rs * gv[nt] + bev[nt];
                o = o < 0.f ? 0.f : o;
                h[rbase + colbase + nt * 16] = f2bf(o);
            }
        }
}

// ---------------- qkv GEMM (K=128, Mtot=768): Q,K -> packed [bh][256][64]; V -> vT [bh][64][256] ----------------

__global__ __launch_bounds__(256) void gemm_qkv(const u16* __restrict__ A,
                                                const u16* __restrict__ BT,
                                                u16* __restrict__ qP,
                                                u16* __restrict__ kP,
                                                u16* __restrict__ vT) {
    __shared__ __align__(16) u16 lds[8192];
    char* ldsc = (char*)lds;
    int t = threadIdx.x, lane = t & 63, wid = t >> 6;
    int row0 = blockIdx.x * 128, col0 = blockIdx.y * 128;

    f32x4 zero = {0.f, 0.f, 0.f, 0.f};
    f32x4 acc[4][4];
#pragma unroll
    for (int mt = 0; mt < 4; ++mt)
#pragma unroll
        for (int nt = 0; nt < 4; ++nt) acc[mt][nt] = zero;

    int wr = wid >> 1, wc = wid & 1;
    int rA = wr * 64 + (lane & 15);
    int rB = wc * 64 + (lane & 15);
    int kch = (lane >> 4) << 4;

    for (int kt = 0; kt < 4; ++kt) {
        int kc = kt << 5;
#pragma unroll
        for (int i = 0; i < 2; ++i) {
            int off = wid * 2048 + i * 1024 + lane * 16;
            int r = off >> 6, cb = off & 63;
            __builtin_amdgcn_global_load_lds((const u32*)((const char*)A + ((size_t)(row0 + r) * 128 + kc) * 2 + cb),
                                             (u32*)(ldsc + wid * 2048 + i * 1024), 16, 0, 0);
            __builtin_amdgcn_global_load_lds((const u32*)((const char*)BT + ((size_t)(col0 + r) * 128 + kc) * 2 + cb),
                                             (u32*)(ldsc + 8192 + wid * 2048 + i * 1024), 16, 0, 0);
        }
        __syncthreads();
        bf16x8 af[4], bfr[4];
#pragma unroll
        for (int mt = 0; mt < 4; ++mt)
            af[mt] = *(const bf16x8*)(ldsc + (rA + mt * 16) * 64 + kch);
#pragma unroll
        for (int nt = 0; nt < 4; ++nt)
            bfr[nt] = *(const bf16x8*)(ldsc + 8192 + (rB + nt * 16) * 64 + kch);
#pragma unroll
        for (int mt = 0; mt < 4; ++mt)
#pragma unroll
            for (int nt = 0; nt < 4; ++nt)
                acc[mt][nt] = __builtin_amdgcn_mfma_f32_16x16x32_bf16(af[mt], bfr[nt], acc[mt][nt], 0, 0, 0);
        __syncthreads();
    }

    int colb = col0 + wc * 64 + (lane & 15);
    int rowb = row0 + wr * 64 + ((lane >> 4) << 2);
    int bb = row0 >> 8;
    if (col0 < 512) {
        u16* dst = (col0 < 256) ? qP : kP;
#pragma unroll
        for (int mt = 0; mt < 4; ++mt) {
#pragma unroll
            for (int nt = 0; nt < 4; ++nt) {
                int c = (colb + nt * 16) & 255;
                int hh = c >> 6, d = c & 63;
#pragma unroll
                for (int r = 0; r < 4; ++r) {
                    int node = (rowb + mt * 16 + r) & 255;
                    dst[(size_t)(bb * 4 + hh) * 16384 + node * 64 + d] = f2bf(acc[mt][nt][r]);
                }
            }
        }
    } else {
#pragma unroll
        for (int mt = 0; mt < 4; ++mt) {
            int node0 = (rowb + mt * 16) & 255;
#pragma unroll
            for (int nt = 0; nt < 4; ++nt) {
                int c = colb + nt * 16 - 512;
                int hh = c >> 6, d = c & 63;
                u16 tmp[4];
#pragma unroll
                for (int r = 0; r < 4; ++r) tmp[r] = f2bf(acc[mt][nt][r]);
                *(ushort4*)(vT + (size_t)(bb * 4 + hh) * 16384 + d * 256 + node0) = *(ushort4*)tmp;
            }
        }
    }
}

// ---------------- final projection GEMM (K=128, f32 out + bias) ----------------

__global__ __launch_bounds__(256) void gemm_proj(const u16* __restrict__ A,
                                                 const u16* __restrict__ BT,
                                                 float* __restrict__ Out,
                                                 const float* __restrict__ bias) {
    __shared__ __align__(16) u16 lds[8192];
    char* ldsc = (char*)lds;
    int t = threadIdx.x, lane = t & 63, wid = t >> 6;
    int row0 = blockIdx.x * 128;

    f32x4 zero = {0.f, 0.f, 0.f, 0.f};
    f32x4 acc[4][4];
#pragma unroll
    for (int mt = 0; mt < 4; ++mt)
#pragma unroll
        for (int nt = 0; nt < 4; ++nt) acc[mt][nt] = zero;

    int wr = wid >> 1, wc = wid & 1;
    int rA = wr * 64 + (lane & 15);
    int rB = wc * 64 + (lane & 15);
    int kch = (lane >> 4) << 4;

    for (int kt = 0; kt < 4; ++kt) {
        int kc = kt << 5;
#pragma unroll
        for (int i = 0; i < 2; ++i) {
            int off = wid * 2048 + i * 1024 + lane * 16;
            int r = off >> 6, cb = off & 63;
            __builtin_amdgcn_global_load_lds((const u32*)((const char*)A + ((size_t)(row0 + r) * 128 + kc) * 2 + cb),
                                             (u32*)(ldsc + wid * 2048 + i * 1024), 16, 0, 0);
            __builtin_amdgcn_global_load_lds((const u32*)((const char*)BT + ((size_t)r * 128 + kc) * 2 + cb),
                                             (u32*)(ldsc + 8192 + wid * 2048 + i * 1024), 16, 0, 0);
        }
        __syncthreads();
        bf16x8 af[4], bfr[4];
#pragma unroll
        for (int mt = 0; mt < 4; ++mt)
            af[mt] = *(const bf16x8*)(ldsc + (rA + mt * 16) * 64 + kch);
#pragma unroll
        for (int nt = 0; nt < 4; ++nt)
            bfr[nt] = *(const bf16x8*)(ldsc + 8192 + (rB + nt * 16) * 64 + kch);
#pragma unroll
        for (int mt = 0; mt < 4; ++mt)
#pragma unroll
            for (int nt = 0; nt < 4; ++nt)
                acc[mt][nt] = __builtin_amdgcn_mfma_f32_16x16x32_bf16(af[mt], bfr[nt], acc[mt][nt], 0, 0, 0);
        __syncthreads();
    }

    int colb = wc * 64 + (lane & 15);
    int rowb = row0 + wr * 64 + ((lane >> 4) << 2);
#pragma unroll
    for (int mt = 0; mt < 4; ++mt)
#pragma unroll
        for (int nt = 0; nt < 4; ++nt)
#pragma unroll
            for (int r = 0; r < 4; ++r)
                Out[(size_t)(rowb + mt * 16 + r) * 128 + colb + nt * 16] =
                    acc[mt][nt][r] + bias[colb + nt * 16];
}

// ---------------- fc GEMM: fused LN -> +residual -> LN; writes h AND hT (for next layer's agg) ----------------

__global__ __launch_bounds__(256) void gemm_fc_ln2(const u16* __restrict__ A,
                                                   const u16* __restrict__ BT,
                                                   const float* __restrict__ mg,
                                                   const float* __restrict__ mb,
                                                   const float* __restrict__ eg,
                                                   const float* __restrict__ eb,
                                                   u16* __restrict__ h,
                                                   u16* __restrict__ hT) {
    __shared__ __align__(16) u16 lds[8192];
    char* ldsc = (char*)lds;
    int t = threadIdx.x, lane = t & 63, wid = t >> 6;
    int row0 = blockIdx.x * 128;

    f32x4 zero = {0.f, 0.f, 0.f, 0.f};
    f32x4 acc[4][4];
#pragma unroll
    for (int mt = 0; mt < 4; ++mt)
#pragma unroll
        for (int nt = 0; nt < 4; ++nt) acc[mt][nt] = zero;

    int wr = wid >> 1, wc = wid & 1;
    int rA = wr * 64 + (lane & 15);
    int rB = wc * 64 + (lane & 15);
    int kch = (lane >> 4) << 4;

    for (int kt = 0; kt < 8; ++kt) {
        int kc = kt << 5;
#pragma unroll
        for (int i = 0; i < 2; ++i) {
            int off = wid * 2048 + i * 1024 + lane * 16;
            int r = off >> 6, cb = off & 63;
            __builtin_amdgcn_global_load_lds((const u32*)((const char*)A + ((size_t)(row0 + r) * 256 + kc) * 2 + cb),
                                             (u32*)(ldsc + wid * 2048 + i * 1024), 16, 0, 0);
            __builtin_amdgcn_global_load_lds((const u32*)((const char*)BT + ((size_t)r * 256 + kc) * 2 + cb),
                                             (u32*)(ldsc + 8192 + wid * 2048 + i * 1024), 16, 0, 0);
        }
        __syncthreads();
        bf16x8 af[4], bfr[4];
#pragma unroll
        for (int mt = 0; mt < 4; ++mt)
            af[mt] = *(const bf16x8*)(ldsc + (rA + mt * 16) * 64 + kch);
#pragma unroll
        for (int nt = 0; nt < 4; ++nt)
            bfr[nt] = *(const bf16x8*)(ldsc + 8192 + (rB + nt * 16) * 64 + kch);
#pragma unroll
        for (int mt = 0; mt < 4; ++mt)
#pragma unroll
            for (int nt = 0; nt < 4; ++nt)
                acc[mt][nt] = __builtin_amdgcn_mfma_f32_16x16x32_bf16(af[mt], bfr[nt], acc[mt][nt], 0, 0, 0);
        __syncthreads();
    }

    float* redS  = (float*)ldsc;
    float* redQ  = (float*)(ldsc + 2048);
    float* redS2 = (float*)(ldsc + 4096);
    float* redQ2 = (float*)(ldsc + 6144);
    int colbase = wc * 64 + (lane & 15);
    int qrow = (lane >> 4) << 2;
    float mgv[4], mbv[4], egv[4], ebv[4];
#pragma unroll
    for (int nt = 0; nt < 4; ++nt) {
        int c = colbase + nt * 16;
        mgv[nt] = mg[c]; mbv[nt] = mb[c]; egv[nt] = eg[c]; ebv[nt] = eb[c];
    }
#pragma unroll
    for (int mt = 0; mt < 4; ++mt)
#pragma unroll
        for (int r = 0; r < 4; ++r) {
            float s = 0.f, q = 0.f;
#pragma unroll
            for (int nt = 0; nt < 4; ++nt) {
                float v = acc[mt][nt][r];
                s += v; q += v * v;
            }
            s = red16(s); q = red16(q);
            if ((lane & 15) == 0) {
                int lr = wr * 64 + qrow + mt * 16 + r;
                redS[lr * 2 + wc] = s; redQ[lr * 2 + wc] = q;
            }
        }
    __syncthreads();
#pragma unroll
    for (int mt = 0; mt < 4; ++mt)
#pragma unroll
        for (int r = 0; r < 4; ++r) {
            int lr = wr * 64 + qrow + mt * 16 + r;
            float mu = (redS[lr * 2] + redS[lr * 2 + 1]) * (1.f / 128.f);
            float var = (redQ[lr * 2] + redQ[lr * 2 + 1]) * (1.f / 128.f) - mu * mu;
            float rs = rsqrtf(var + 1e-5f);
            size_t rbase = (size_t)(row0 + lr) * 128;
            float s2 = 0.f, q2 = 0.f;
#pragma unroll
            for (int nt = 0; nt < 4; ++nt) {
                float o = (acc[mt][nt][r] - mu) * rs * mgv[nt] + mbv[nt];
                float z = o + bf2f(h[rbase + colbase + nt * 16]);
                acc[mt][nt][r] = z;
                s2 += z; q2 += z * z;
            }
            s2 = red16(s2); q2 = red16(q2);
            if ((lane & 15) == 0) {
                redS2[lr * 2 + wc] = s2; redQ2[lr * 2 + wc] = q2;
            }
        }
    __syncthreads();
    int bb = row0 >> 8;
#pragma unroll
    for (int mt = 0; mt < 4; ++mt) {
        u16 tvals[4][4];   // [nt][r]
#pragma unroll
        for (int r = 0; r < 4; ++r) {
            int lr = wr * 64 + qrow + mt * 16 + r;
            float mu = (redS2[lr * 2] + redS2[lr * 2 + 1]) * (1.f / 128.f);
            float var = (redQ2[lr * 2] + redQ2[lr * 2 + 1]) * (1.f / 128.f) - mu * mu;
            float rs = rsqrtf(var + 1e-5f);
            size_t rbase = (size_t)(row0 + lr) * 128;
#pragma unroll
            for (int nt = 0; nt < 4; ++nt) {
                float z = acc[mt][nt][r];
                u16 o = f2bf((z - mu) * rs * egv[nt] + ebv[nt]);
                h[rbase + colbase + nt * 16] = o;
                tvals[nt][r] = o;
            }
        }
        int node0 = ((row0 & 255) + wr * 64 + qrow + mt * 16);
#pragma unroll
        for (int nt = 0; nt < 4; ++nt) {
            int d = colbase + nt * 16;
            *(ushort4*)(hT + (size_t)bb * 32768 + (size_t)d * 256 + node0) = *(ushort4*)tvals[nt];
        }
    }
}

// ---------------- fused attention: per (b, head, qhalf) block; packed Q/K/V; bf16 mat; P in registers ----------------
// grid (NB, 4, 2): 1024 blocks -> 2 scheduling rounds, staging overlaps compute across rounds.

__global__ __launch_bounds__(512) void attn_k(const u16* __restrict__ qP,
                                              const u16* __restrict__ kP,
                                              const u16* __restrict__ vT,
                                              const u16* __restrict__ matB,
                                              u16* __restrict__ ctx) {
    __shared__ __align__(16) u16 Kl[256 * 72];   // 36864 B (padded rows)
    __shared__ __align__(16) u16 Vl[64 * 264];   // 33792 B (padded rows)
    int t = threadIdx.x, lane = t & 63, w = t >> 6;
    int b = blockIdx.x, hh = blockIdx.y, zh = blockIdx.z;
    int bh = b * 4 + hh;
    int lg = lane >> 4, q16 = lane & 15;
    int qrow_l = zh * 128 + w * 16;

    // Q-fragment load hoisted above the barrier (global, independent of LDS staging)
    const u16* qsrc = qP + (size_t)bh * 16384 + (qrow_l + q16) * 64 + (lg << 3);
    bf16x8 aq0 = *(const bf16x8*)(qsrc);
    bf16x8 aq1 = *(const bf16x8*)(qsrc + 32);

    // --- staging from packed buffers (dense 32KB each), all 512 threads ---
    {
        const u16* kb = kP + (size_t)bh * 16384;
#pragma unroll
        for (int i = 0; i < 4; ++i) {
            int idx = i * 512 + t;              // 2048 x 16B; K row = 64 u16 = 8 chunks
            int node = idx >> 3, oct = idx & 7;
            *(uint4*)(Kl + node * 72 + oct * 8) = *(const uint4*)(kb + node * 64 + oct * 8);
        }
        const u16* vb = vT + (size_t)bh * 16384;
#pragma unroll
        for (int i = 0; i < 4; ++i) {
            int idx = i * 512 + t;              // 2048 x 16B; V row = 256 u16 = 32 chunks
            int d = idx >> 5, p = idx & 31;
            *(uint4*)(Vl + d * 264 + p * 8) = *(const uint4*)(vb + d * 256 + p * 8);
        }
    }
    __syncthreads();

    f32x4 zero = {0.f, 0.f, 0.f, 0.f};
    bool loA = (lg < 2);
    int s01 = q16 + ((lg & 1) << 5);
    int s23 = s01 + 16;

    f32x4 sc[16];
    __builtin_amdgcn_s_setprio(1);
#pragma unroll
    for (int nt = 0; nt < 16; ++nt) {
        const u16* ks = Kl + (nt * 16 + q16) * 72 + (lg << 3);
        bf16x8 k0 = *(const bf16x8*)(ks);
        bf16x8 k1 = *(const bf16x8*)(ks + 32);
        f32x4 a = __builtin_amdgcn_mfma_f32_16x16x32_bf16(k0, aq0, zero, 0, 0, 0);
        a = __builtin_amdgcn_mfma_f32_16x16x32_bf16(k1, aq1, a, 0, 0, 0);
        sc[nt] = a;
    }
    __builtin_amdgcn_s_setprio(0);

    const u16* mrow = matB + ((size_t)b * LL + qrow_l + q16) * LL + (lg << 2);
#pragma unroll
    for (int nt = 0; nt < 16; ++nt) {
        ushort4 mv = *(const ushort4*)(mrow + nt * 16);
        sc[nt][0] *= bf2f(mv.x);
        sc[nt][1] *= bf2f(mv.y);
        sc[nt][2] *= bf2f(mv.z);
        sc[nt][3] *= bf2f(mv.w);
    }

    float mx = -1e30f;
#pragma unroll
    for (int nt = 0; nt < 16; ++nt)
#pragma unroll
        for (int r = 0; r < 4; ++r) mx = fmaxf(mx, sc[nt][r]);
    mx = fmaxf(mx, __shfl_xor(mx, 16, 64));
    mx = fmaxf(mx, __shfl_xor(mx, 32, 64));
    float sm = 0.f;
#pragma unroll
    for (int nt = 0; nt < 16; ++nt)
#pragma unroll
        for (int r = 0; r < 4; ++r) {
            float e = __expf(sc[nt][r] - mx);
            sc[nt][r] = e;
            sm += e;
        }
    sm += __shfl_xor(sm, 16, 64);
    sm += __shfl_xor(sm, 32, 64);
    float inv = 1.f / sm;
#pragma unroll
    for (int nt = 0; nt < 16; ++nt)
#pragma unroll
        for (int r = 0; r < 4; ++r) sc[nt][r] *= inv;

    f32x4 oa[4];
#pragma unroll
    for (int dt = 0; dt < 4; ++dt) oa[dt] = zero;
    __builtin_amdgcn_s_setprio(1);
#pragma unroll
    for (int kt = 0; kt < 8; ++kt) {
        u32 A0 = cvtpk(sc[2 * kt][0], sc[2 * kt][1]);
        u32 A1 = cvtpk(sc[2 * kt][2], sc[2 * kt][3]);
        u32 B0 = cvtpk(sc[2 * kt + 1][0], sc[2 * kt + 1][1]);
        u32 B1 = cvtpk(sc[2 * kt + 1][2], sc[2 * kt + 1][3]);
        u32 a0s = bperm(s01, A0), b0s = bperm(s01, B0);
        u32 a1s = bperm(s01, A1), b1s = bperm(s01, B1);
        u32 a0t = bperm(s23, A0), b0t = bperm(s23, B0);
        u32 a1t = bperm(s23, A1), b1t = bperm(s23, B1);
        union { u32 u[4]; bf16x8 v; } pa;
        pa.u[0] = loA ? a0s : b0s;
        pa.u[1] = loA ? a1s : b1s;
        pa.u[2] = loA ? a0t : b0t;
        pa.u[3] = loA ? a1t : b1t;
#pragma unroll
        for (int dt = 0; dt < 4; ++dt) {
            bf16x8 bv = *(const bf16x8*)(Vl + (dt * 16 + q16) * 264 + kt * 32 + (lg << 3));
            oa[dt] = __builtin_amdgcn_mfma_f32_16x16x32_bf16(pa.v, bv, oa[dt], 0, 0, 0);
        }
    }
    __builtin_amdgcn_s_setprio(0);
#pragma unroll
    for (int dt = 0; dt < 4; ++dt)
#pragma unroll
        for (int r = 0; r < 4; ++r)
            ctx[(size_t)(b * LL + qrow_l + (lg << 2) + r) * 256 + hh * 64 + dt * 16 + q16] = f2bf(oa[dt][r]);
}

// ---------------- host launch ----------------

extern "C" void kernel_launch(void* const* d_in, const int* in_sizes, int n_in,
                              void* d_out, int out_size, void* d_ws, size_t ws_size,
                              hipStream_t stream) {
    (void)out_size; (void)ws_size; (void)n_in;
    const float* x        = (const float*)d_in[0];
    const int*   ei       = (const int*)d_in[1];
    const float* ea       = (const float*)d_in[2];
    const float* adj      = (const float*)d_in[3];
    const float* dis      = (const float*)d_in[4];
    int pb = (in_sizes[5] == 5120) ? 5 : 6;
    const float* g0_rel_w = (const float*)d_in[pb + 0];
    const float* g0_rel_b = (const float*)d_in[pb + 1];
    const float* g0_root_w= (const float*)d_in[pb + 2];
    const float* g_rel_w  = (const float*)d_in[pb + 3];
    const float* g_rel_b  = (const float*)d_in[pb + 4];
    const float* g_root_w = (const float*)d_in[pb + 5];
    const float* nm_g     = (const float*)d_in[pb + 6];
    const float* nm_b     = (const float*)d_in[pb + 7];
    const float* wq       = (const float*)d_in[pb + 8];
    const float* wk       = (const float*)d_in[pb + 9];
    const float* wv       = (const float*)d_in[pb + 10];
    const float* fc       = (const float*)d_in[pb + 11];
    const float* mha_g    = (const float*)d_in[pb + 12];
    const float* mha_b    = (const float*)d_in[pb + 13];
    const float* enc_g    = (const float*)d_in[pb + 14];
    const float* enc_b    = (const float*)d_in[pb + 15];
    const float* proj_w   = (const float*)d_in[pb + 16];
    const float* proj_b   = (const float*)d_in[pb + 17];
    const int* srcI = ei;
    const int* dstI = ei + EDGES;

    char* w = (char*)d_ws;
    float* Wf     = (float*)w; w += (size_t)33554432;   // W f32 scatter, then reused as matB (bf16)
    u16*   ctx    = (u16*)w;   w += (size_t)16777216;   // attn output [N,256]
    u16*   h      = (u16*)w;   w += (size_t)8388608;
    u16*   qP     = (u16*)w;   w += (size_t)16777216;   // packed Q [bh][256][64]
    u16*   kP     = (u16*)w;   w += (size_t)16777216;   // packed K [bh][256][64]
    u16*   Wb     = (u16*)w;   w += (size_t)16777216;   // W bf16 [128][256][256]
    u16*   bigT   = (u16*)w;   w += (size_t)16777216;   // hT (8.4MB) / vT (16.7MB), time-disjoint
    u16* wconvT0  = (u16*)w;   w += (size_t)32768;
    u16* wconvT   = (u16*)w;   w += (size_t)196608;
    u16* wqkvT    = (u16*)w;   w += (size_t)786432;
    u16* fcT      = (u16*)w;   w += (size_t)262144;
    u16* projT    = (u16*)w;   w += (size_t)32768;
    u16*   matB = (u16*)Wf;
    u16*   hT  = bigT;
    u16*   vT  = bigT;

    // --- prep (cast MUST precede build_matrix: matB aliases Wf) ---
    zero_wf_k<<<8192, 256, 0, stream>>>((float4*)Wf);
    scatter_w_k<<<2048, 256, 0, stream>>>(srcI, dstI, ea, Wf);
    cast_w_k<<<8192, 256, 0, stream>>>(Wf, Wb);
    build_matrix_k<<<32768, 256, 0, stream>>>(adj, dis, matB);
    prep_weights_k<<<2560, 256, 0, stream>>>(g0_rel_w, g0_root_w, g_rel_w, g_root_w,
                                             wq, wk, wv, fc, proj_w,
                                             wconvT0, wconvT, wqkvT, fcT, projT);
    transpose_x_k<<<2048, 256, 0, stream>>>(x, hT);

    for (int L = 0; L < 4; ++L) {
        if (L == 0)
            gemm_agg_conv<true><<<256, 256, 0, stream>>>(Wb, hT, x, h, wconvT0,
                                                         g0_rel_b, nm_g, nm_b);
        else
            gemm_agg_conv<false><<<256, 256, 0, stream>>>(Wb, hT, x, h, wconvT + (L - 1) * 32768,
                                                          g_rel_b + (L - 1) * 128,
                                                          nm_g + L * 128, nm_b + L * 128);
        gemm_qkv<<<dim3(256, 6), 256, 0, stream>>>(h, wqkvT + L * 98304, qP, kP, vT);
        attn_k<<<dim3(NB, 4, 2), 512, 0, stream>>>(qP, kP, vT, matB, ctx);
        gemm_fc_ln2<<<256, 256, 0, stream>>>(ctx, fcT + L * 32768,
                                             mha_g + L * 128, mha_b + L * 128,
                                             enc_g + L * 128, enc_b + L * 128, h, hT);
    }
    gemm_proj<<<256, 256, 0, stream>>>(h, projT, (float*)d_out, proj_b);
}

// Round 19
// 448.212 us; speedup vs baseline: 1.1665x; 1.0557x over previous
//
#include <hip/hip_runtime.h>
#include <stdint.h>

typedef unsigned short u16;
typedef unsigned int u32;
typedef __attribute__((ext_vector_type(4))) float f32x4;
typedef __attribute__((ext_vector_type(8))) short bf16x8;

#define NB 128      // graphs
#define LL 256      // nodes per graph
#define DD 128      // hidden
#define EDGES 524288
#define EPG 4096    // edges per graph
#define NN (NB*LL)

__device__ __forceinline__ float bf2f(u16 u) {
    union { u32 i; float f; } v; v.i = ((u32)u) << 16; return v.f;
}
__device__ __forceinline__ u16 f2bf(float f) {
    union { float f; u32 i; } v; v.f = f;
    u32 i = v.i;
    u32 r = (i + 0x7fffu + ((i >> 16) & 1u)) >> 16;   // RNE
    return (u16)r;
}
__device__ __forceinline__ float matfn(float a, float dv) {
    if (a != 0.f) return (a == 1.2f) ? 1.1f : a;
    return (dv == 0.f) ? 0.f : exp2f((1.f - dv) * 0.5849625007211562f); // 1.5^(1-dis)
}
__device__ __forceinline__ float red16(float v) {
#pragma unroll
    for (int off = 1; off < 16; off <<= 1) v += __shfl_xor(v, off, 64);
    return v;
}
__device__ __forceinline__ u32 cvtpk(float lo, float hi) {
    u32 r;
    asm("v_cvt_pk_bf16_f32 %0, %1, %2" : "=v"(r) : "v"(lo), "v"(hi));
    return r;
}
__device__ __forceinline__ u32 bperm(int srcLane, u32 v) {
    return (u32)__builtin_amdgcn_ds_bpermute(srcLane << 2, (int)v);
}

// ---------------- prep kernels ----------------

// zero the 32 MiB Wf region with float4 stores
__global__ __launch_bounds__(256) void zero_wf_k(float4* __restrict__ p) {
    p[blockIdx.x * 256 + threadIdx.x] = make_float4(0.f, 0.f, 0.f, 0.f);
}

__global__ __launch_bounds__(256) void scatter_w_k(const int* __restrict__ srcI,
                                                   const int* __restrict__ dstI,
                                                   const float* __restrict__ ew,
                                                   float* __restrict__ Wf) {
    int e = blockIdx.x * 256 + threadIdx.x;
    if (e >= EDGES) return;
    int b = e >> 12;
    atomicAdd(&Wf[(size_t)b * 65536 + (size_t)(dstI[e] & 255) * 256 + (srcI[e] & 255)], ew[e]);
}

// NOTE: must run BEFORE build_matrix_k (matB aliases Wf).
__global__ __launch_bounds__(256) void cast_w_k(const float* __restrict__ Wf, u16* __restrict__ Wb) {
    int i = blockIdx.x * 256 + threadIdx.x;
    float4 v = ((const float4*)Wf)[i];
    ushort4 o;
    o.x = f2bf(v.x); o.y = f2bf(v.y); o.z = f2bf(v.z); o.w = f2bf(v.w);
    ((ushort4*)Wb)[i] = o;
}

// matB holds bf16(0.125 * matfn) (attn scale folded in)
__global__ __launch_bounds__(256) void build_matrix_k(const float* __restrict__ adj,
                                                      const float* __restrict__ dis,
                                                      u16* __restrict__ matB) {
    int i = blockIdx.x * 256 + threadIdx.x;
    matB[i] = f2bf(0.125f * matfn(adj[i], dis[i]));
}

// all weight transposes in one kernel (655360 elements, 2560 blocks)
__global__ __launch_bounds__(256) void prep_weights_k(
        const float* __restrict__ g0_rel_w, const float* __restrict__ g0_root_w,
        const float* __restrict__ g_rel_w,  const float* __restrict__ g_root_w,
        const float* __restrict__ wq, const float* __restrict__ wk,
        const float* __restrict__ wv, const float* __restrict__ fc,
        const float* __restrict__ proj_w,
        u16* __restrict__ wconvT0, u16* __restrict__ wconvT,
        u16* __restrict__ wqkvT, u16* __restrict__ fcT, u16* __restrict__ projT) {
    int i = blockIdx.x * 256 + threadIdx.x;
    if (i < 16384) {
        int m = i >> 7, k = i & 127;
        float v = 0.f;
        if (k < 40) v = g0_rel_w[k * 128 + m];
        else if (k >= 64 && k < 104) v = g0_root_w[(k - 64) * 128 + m];
        wconvT0[i] = f2bf(v);
        return;
    }
    i -= 16384;
    if (i < 98304) {
        int l = i >> 15, jj = i & 32767;
        int m = jj >> 8, k = jj & 255;
        float v = (k < 128) ? g_rel_w[l * 16384 + k * 128 + m]
                            : g_root_w[l * 16384 + (k - 128) * 128 + m];
        wconvT[i] = f2bf(v);
        return;
    }
    i -= 98304;
    if (i < 393216) {
        int l = i / 98304, jj = i % 98304;
        int m = jj >> 7, k = jj & 127;
        const float* s = (m < 256) ? wq : (m < 512) ? wk : wv;
        int mm = m & 255;
        wqkvT[i] = f2bf(s[l * 32768 + k * 256 + mm]);
        return;
    }
    i -= 393216;
    if (i < 131072) {
        int l = i >> 15, jj = i & 32767;
        int m = jj >> 8, k = jj & 255;
        fcT[i] = f2bf(fc[l * 32768 + k * 128 + m]);
        return;
    }
    i -= 131072;
    {
        int m = i >> 7, k = i & 127;
        projT[i] = f2bf(proj_w[k * 128 + m]);
    }
}

// layer-0 transpose: x [N,40] f32 (zero-padded to 128) -> hT [b][128][256]
__global__ __launch_bounds__(256) void transpose_x_k(const float* __restrict__ x,
                                                     u16* __restrict__ hT) {
    int gw = blockIdx.x * 4 + (threadIdx.x >> 6);
    int lane = threadIdx.x & 63;
    int b = gw >> 6, rem = gw & 63, db = rem >> 5, jb = rem & 31;
    int d = (db << 6) + lane;
    u16 vals[8];
#pragma unroll
    for (int jj = 0; jj < 8; ++jj) {
        int node = (b << 8) + (jb << 3) + jj;
        vals[jj] = (d < 40) ? f2bf(x[(size_t)node * 40 + d]) : (u16)0;
    }
    *(uint4*)(hT + (size_t)b * 32768 + (size_t)d * 256 + (jb << 3)) = *(uint4*)vals;
}

// ---------------- FUSED per-graph agg GEMM + conv GEMM + bias+LN+relu ----------------
// 512 threads = 8 waves; wave (wr=wid>>1, wc=wid&1) owns 32 rows x 64 cols (acc[2][4]).

template<bool IS0>
__global__ __launch_bounds__(512) void gemm_agg_conv(const u16* __restrict__ Wb,
                                                     const u16* __restrict__ BT0,
                                                     const float* __restrict__ x,
                                                     u16* h,
                                                     const u16* __restrict__ BTc,
                                                     const float* __restrict__ rb,
                                                     const float* __restrict__ g,
                                                     const float* __restrict__ be) {
    __shared__ __align__(16) u16 lds[8192 + 128 * 136];   // 16KB stage + 34816B aggT
    char* ldsc = (char*)lds;
    u16* aggT = lds + 8192;
    int t = threadIdx.x, lane = t & 63, wid = t >> 6;
    int b = blockIdx.x >> 1, rt = blockIdx.x & 1;
    int row0 = rt << 7, nbase = b << 8;
    const u16* A = Wb + (size_t)b * 65536 + (size_t)row0 * 256;
    const u16* BT = BT0 + (size_t)b * 32768;

    f32x4 zero = {0.f, 0.f, 0.f, 0.f};
    f32x4 acc[2][4];
#pragma unroll
    for (int mt = 0; mt < 2; ++mt)
#pragma unroll
        for (int nt = 0; nt < 4; ++nt) acc[mt][nt] = zero;

    int wr = wid >> 1, wc = wid & 1;
    int rA = wr * 32 + (lane & 15);
    int rB = wc * 64 + (lane & 15);
    int kch = (lane >> 4) << 4;
    int soff = wid * 1024 + lane * 16;       // 8KB covered by 8 waves
    int sr = soff >> 6, scb = soff & 63;     // staged row, byte-in-row

    // ---- Phase A: agg GEMM (K=256) ----
    for (int kt = 0; kt < 8; ++kt) {
        int kc = kt << 5;
        __builtin_amdgcn_global_load_lds((const u32*)((const char*)A + ((size_t)sr * 256 + kc) * 2 + scb),
                                         (u32*)(ldsc + wid * 1024), 16, 0, 0);
        __builtin_amdgcn_global_load_lds((const u32*)((const char*)BT + ((size_t)sr * 256 + kc) * 2 + scb),
                                         (u32*)(ldsc + 8192 + wid * 1024), 16, 0, 0);
        __syncthreads();
        bf16x8 af[2], bfr[4];
#pragma unroll
        for (int mt = 0; mt < 2; ++mt)
            af[mt] = *(const bf16x8*)(ldsc + (rA + mt * 16) * 64 + kch);
#pragma unroll
        for (int nt = 0; nt < 4; ++nt)
            bfr[nt] = *(const bf16x8*)(ldsc + 8192 + (rB + nt * 16) * 64 + kch);
#pragma unroll
        for (int mt = 0; mt < 2; ++mt)
#pragma unroll
            for (int nt = 0; nt < 4; ++nt)
                acc[mt][nt] = __builtin_amdgcn_mfma_f32_16x16x32_bf16(af[mt], bfr[nt], acc[mt][nt], 0, 0, 0);
        __syncthreads();
    }

    // ---- Phase B: acc -> aggT ----
    {
        int colb = wc * 64 + (lane & 15);
        int rowb = wr * 32 + ((lane >> 4) << 2);
#pragma unroll
        for (int mt = 0; mt < 2; ++mt)
#pragma unroll
            for (int nt = 0; nt < 4; ++nt)
#pragma unroll
                for (int r = 0; r < 4; ++r)
                    aggT[(rowb + mt * 16 + r) * 136 + colb + nt * 16] = f2bf(acc[mt][nt][r]);
        if (IS0) {
            for (int idx = t; idx < 128 * 40; idx += 512) {
                int i = idx / 40, c = idx - i * 40;
                aggT[i * 136 + 64 + c] = f2bf(x[(size_t)(nbase + row0 + i) * 40 + c]);
            }
        }
    }
    __syncthreads();

    // ---- Phase C: conv GEMM ----
#pragma unroll
    for (int mt = 0; mt < 2; ++mt)
#pragma unroll
        for (int nt = 0; nt < 4; ++nt) acc[mt][nt] = zero;

    const int NKT = IS0 ? 4 : 8;
    const int KK = IS0 ? 128 : 256;
    for (int kt = 0; kt < NKT; ++kt) {
        int kc = kt << 5;
        bool fromLds = IS0 || (kt < 4);
        if (!fromLds) {
            int kcl = (kt - 4) << 5;
            __builtin_amdgcn_global_load_lds((const u32*)((const char*)h + ((size_t)(nbase + row0 + sr) * 128 + kcl) * 2 + scb),
                                             (u32*)(ldsc + wid * 1024), 16, 0, 0);
        }
        __builtin_amdgcn_global_load_lds((const u32*)((const char*)BTc + ((size_t)sr * KK + kc) * 2 + scb),
                                         (u32*)(ldsc + 8192 + wid * 1024), 16, 0, 0);
        __syncthreads();
        bf16x8 af[2], bfr[4];
        if (fromLds) {
#pragma unroll
            for (int mt = 0; mt < 2; ++mt)
                af[mt] = *(const bf16x8*)((const char*)aggT + (rA + mt * 16) * 272 + kt * 64 + kch);
        } else {
#pragma unroll
            for (int mt = 0; mt < 2; ++mt)
                af[mt] = *(const bf16x8*)(ldsc + (rA + mt * 16) * 64 + kch);
        }
#pragma unroll
        for (int nt = 0; nt < 4; ++nt)
            bfr[nt] = *(const bf16x8*)(ldsc + 8192 + (rB + nt * 16) * 64 + kch);
#pragma unroll
        for (int mt = 0; mt < 2; ++mt)
#pragma unroll
            for (int nt = 0; nt < 4; ++nt)
                acc[mt][nt] = __builtin_amdgcn_mfma_f32_16x16x32_bf16(af[mt], bfr[nt], acc[mt][nt], 0, 0, 0);
        __syncthreads();
    }

    // ---- Phase D: bias + LN + relu -> h ----
    float* redS = (float*)ldsc;
    float* redQ = (float*)(ldsc + 2048);
    int colbase = wc * 64 + (lane & 15);
    int qrow = (lane >> 4) << 2;
    float rbv[4], gv[4], bev[4];
#pragma unroll
    for (int nt = 0; nt < 4; ++nt) {
        int c = colbase + nt * 16;
        rbv[nt] = rb[c]; gv[nt] = g[c]; bev[nt] = be[c];
    }
#pragma unroll
    for (int mt = 0; mt < 2; ++mt)
#pragma unroll
        for (int r = 0; r < 4; ++r) {
            float s = 0.f, q = 0.f;
#pragma unroll
            for (int nt = 0; nt < 4; ++nt) {
                float v = acc[mt][nt][r] + rbv[nt];
                s += v; q += v * v;
            }
            s = red16(s); q = red16(q);
            if ((lane & 15) == 0) {
                int lr = wr * 32 + qrow + mt * 16 + r;
                redS[lr * 2 + wc] = s; redQ[lr * 2 + wc] = q;
            }
        }
    __syncthreads();
#pragma unroll
    for (int mt = 0; mt < 2; ++mt)
#pragma unroll
        for (int r = 0; r < 4; ++r) {
            int lr = wr * 32 + qrow + mt * 16 + r;
            float mu = (redS[lr * 2] + redS[lr * 2 + 1]) * (1.f / 128.f);
            float var = (redQ[lr * 2] + redQ[lr * 2 + 1]) * (1.f / 128.f) - mu * mu;
            float rs = rsqrtf(var + 1e-5f);
            size_t rbase = (size_t)(nbase + row0 + lr) * 128;
#pragma unroll
            for (int nt = 0; nt < 4; ++nt) {
                float v = acc[mt][nt][r] + rbv[nt];
                float o = (v - mu) * rs * gv[nt] + bev[nt];
                o = o < 0.f ? 0.f : o;
                h[rbase + colbase + nt * 16] = f2bf(o);
            }
        }
}

// ---------------- qkv GEMM (K=128, Mtot=768): Q,K -> packed [bh][256][64]; V -> vT [bh][64][256] ----------------

__global__ __launch_bounds__(256) void gemm_qkv(const u16* __restrict__ A,
                                                const u16* __restrict__ BT,
                                                u16* __restrict__ qP,
                                                u16* __restrict__ kP,
                                                u16* __restrict__ vT) {
    __shared__ __align__(16) u16 lds[8192];
    char* ldsc = (char*)lds;
    int t = threadIdx.x, lane = t & 63, wid = t >> 6;
    int row0 = blockIdx.x * 128, col0 = blockIdx.y * 128;

    f32x4 zero = {0.f, 0.f, 0.f, 0.f};
    f32x4 acc[4][4];
#pragma unroll
    for (int mt = 0; mt < 4; ++mt)
#pragma unroll
        for (int nt = 0; nt < 4; ++nt) acc[mt][nt] = zero;

    int wr = wid >> 1, wc = wid & 1;
    int rA = wr * 64 + (lane & 15);
    int rB = wc * 64 + (lane & 15);
    int kch = (lane >> 4) << 4;

    for (int kt = 0; kt < 4; ++kt) {
        int kc = kt << 5;
#pragma unroll
        for (int i = 0; i < 2; ++i) {
            int off = wid * 2048 + i * 1024 + lane * 16;
            int r = off >> 6, cb = off & 63;
            __builtin_amdgcn_global_load_lds((const u32*)((const char*)A + ((size_t)(row0 + r) * 128 + kc) * 2 + cb),
                                             (u32*)(ldsc + wid * 2048 + i * 1024), 16, 0, 0);
            __builtin_amdgcn_global_load_lds((const u32*)((const char*)BT + ((size_t)(col0 + r) * 128 + kc) * 2 + cb),
                                             (u32*)(ldsc + 8192 + wid * 2048 + i * 1024), 16, 0, 0);
        }
        __syncthreads();
        bf16x8 af[4], bfr[4];
#pragma unroll
        for (int mt = 0; mt < 4; ++mt)
            af[mt] = *(const bf16x8*)(ldsc + (rA + mt * 16) * 64 + kch);
#pragma unroll
        for (int nt = 0; nt < 4; ++nt)
            bfr[nt] = *(const bf16x8*)(ldsc + 8192 + (rB + nt * 16) * 64 + kch);
#pragma unroll
        for (int mt = 0; mt < 4; ++mt)
#pragma unroll
            for (int nt = 0; nt < 4; ++nt)
                acc[mt][nt] = __builtin_amdgcn_mfma_f32_16x16x32_bf16(af[mt], bfr[nt], acc[mt][nt], 0, 0, 0);
        __syncthreads();
    }

    int colb = col0 + wc * 64 + (lane & 15);
    int rowb = row0 + wr * 64 + ((lane >> 4) << 2);
    int bb = row0 >> 8;
    if (col0 < 512) {
        u16* dst = (col0 < 256) ? qP : kP;
#pragma unroll
        for (int mt = 0; mt < 4; ++mt) {
#pragma unroll
            for (int nt = 0; nt < 4; ++nt) {
                int c = (colb + nt * 16) & 255;
                int hh = c >> 6, d = c & 63;
#pragma unroll
                for (int r = 0; r < 4; ++r) {
                    int node = (rowb + mt * 16 + r) & 255;
                    dst[(size_t)(bb * 4 + hh) * 16384 + node * 64 + d] = f2bf(acc[mt][nt][r]);
                }
            }
        }
    } else {
#pragma unroll
        for (int mt = 0; mt < 4; ++mt) {
            int node0 = (rowb + mt * 16) & 255;
#pragma unroll
            for (int nt = 0; nt < 4; ++nt) {
                int c = colb + nt * 16 - 512;
                int hh = c >> 6, d = c & 63;
                u16 tmp[4];
#pragma unroll
                for (int r = 0; r < 4; ++r) tmp[r] = f2bf(acc[mt][nt][r]);
                *(ushort4*)(vT + (size_t)(bb * 4 + hh) * 16384 + d * 256 + node0) = *(ushort4*)tmp;
            }
        }
    }
}

// ---------------- final projection GEMM (K=128, f32 out + bias) ----------------

__global__ __launch_bounds__(256) void gemm_proj(const u16* __restrict__ A,
                                                 const u16* __restrict__ BT,
                                                 float* __restrict__ Out,
                                                 const float* __restrict__ bias) {
    __shared__ __align__(16) u16 lds[8192];
    char* ldsc = (char*)lds;
    int t = threadIdx.x, lane = t & 63, wid = t >> 6;
    int row0 = blockIdx.x * 128;

    f32x4 zero = {0.f, 0.f, 0.f, 0.f};
    f32x4 acc[4][4];
#pragma unroll
    for (int mt = 0; mt < 4; ++mt)
#pragma unroll
        for (int nt = 0; nt < 4; ++nt) acc[mt][nt] = zero;

    int wr = wid >> 1, wc = wid & 1;
    int rA = wr * 64 + (lane & 15);
    int rB = wc * 64 + (lane & 15);
    int kch = (lane >> 4) << 4;

    for (int kt = 0; kt < 4; ++kt) {
        int kc = kt << 5;
#pragma unroll
        for (int i = 0; i < 2; ++i) {
            int off = wid * 2048 + i * 1024 + lane * 16;
            int r = off >> 6, cb = off & 63;
            __builtin_amdgcn_global_load_lds((const u32*)((const char*)A + ((size_t)(row0 + r) * 128 + kc) * 2 + cb),
                                             (u32*)(ldsc + wid * 2048 + i * 1024), 16, 0, 0);
            __builtin_amdgcn_global_load_lds((const u32*)((const char*)BT + ((size_t)r * 128 + kc) * 2 + cb),
                                             (u32*)(ldsc + 8192 + wid * 2048 + i * 1024), 16, 0, 0);
        }
        __syncthreads();
        bf16x8 af[4], bfr[4];
#pragma unroll
        for (int mt = 0; mt < 4; ++mt)
            af[mt] = *(const bf16x8*)(ldsc + (rA + mt * 16) * 64 + kch);
#pragma unroll
        for (int nt = 0; nt < 4; ++nt)
            bfr[nt] = *(const bf16x8*)(ldsc + 8192 + (rB + nt * 16) * 64 + kch);
#pragma unroll
        for (int mt = 0; mt < 4; ++mt)
#pragma unroll
            for (int nt = 0; nt < 4; ++nt)
                acc[mt][nt] = __builtin_amdgcn_mfma_f32_16x16x32_bf16(af[mt], bfr[nt], acc[mt][nt], 0, 0, 0);
        __syncthreads();
    }

    int colb = wc * 64 + (lane & 15);
    int rowb = row0 + wr * 64 + ((lane >> 4) << 2);
#pragma unroll
    for (int mt = 0; mt < 4; ++mt)
#pragma unroll
        for (int nt = 0; nt < 4; ++nt)
#pragma unroll
            for (int r = 0; r < 4; ++r)
                Out[(size_t)(rowb + mt * 16 + r) * 128 + colb + nt * 16] =
                    acc[mt][nt][r] + bias[colb + nt * 16];
}

// ---------------- fc GEMM: fused LN -> +residual -> LN; writes h AND hT ----------------
// 512 threads = 8 waves; wave (wr=wid>>1, wc=wid&1) owns 32 rows x 64 cols (acc[2][4]).

__global__ __launch_bounds__(512) void gemm_fc_ln2(const u16* __restrict__ A,
                                                   const u16* __restrict__ BT,
                                                   const float* __restrict__ mg,
                                                   const float* __restrict__ mb,
                                                   const float* __restrict__ eg,
                                                   const float* __restrict__ eb,
                                                   u16* __restrict__ h,
                                                   u16* __restrict__ hT) {
    __shared__ __align__(16) u16 lds[8192];
    char* ldsc = (char*)lds;
    int t = threadIdx.x, lane = t & 63, wid = t >> 6;
    int row0 = blockIdx.x * 128;

    f32x4 zero = {0.f, 0.f, 0.f, 0.f};
    f32x4 acc[2][4];
#pragma unroll
    for (int mt = 0; mt < 2; ++mt)
#pragma unroll
        for (int nt = 0; nt < 4; ++nt) acc[mt][nt] = zero;

    int wr = wid >> 1, wc = wid & 1;
    int rA = wr * 32 + (lane & 15);
    int rB = wc * 64 + (lane & 15);
    int kch = (lane >> 4) << 4;
    int soff = wid * 1024 + lane * 16;
    int sr = soff >> 6, scb = soff & 63;

    for (int kt = 0; kt < 8; ++kt) {
        int kc = kt << 5;
        __builtin_amdgcn_global_load_lds((const u32*)((const char*)A + ((size_t)(row0 + sr) * 256 + kc) * 2 + scb),
                                         (u32*)(ldsc + wid * 1024), 16, 0, 0);
        __builtin_amdgcn_global_load_lds((const u32*)((const char*)BT + ((size_t)sr * 256 + kc) * 2 + scb),
                                         (u32*)(ldsc + 8192 + wid * 1024), 16, 0, 0);
        __syncthreads();
        bf16x8 af[2], bfr[4];
#pragma unroll
        for (int mt = 0; mt < 2; ++mt)
            af[mt] = *(const bf16x8*)(ldsc + (rA + mt * 16) * 64 + kch);
#pragma unroll
        for (int nt = 0; nt < 4; ++nt)
            bfr[nt] = *(const bf16x8*)(ldsc + 8192 + (rB + nt * 16) * 64 + kch);
#pragma unroll
        for (int mt = 0; mt < 2; ++mt)
#pragma unroll
            for (int nt = 0; nt < 4; ++nt)
                acc[mt][nt] = __builtin_amdgcn_mfma_f32_16x16x32_bf16(af[mt], bfr[nt], acc[mt][nt], 0, 0, 0);
        __syncthreads();
    }

    float* redS  = (float*)ldsc;
    float* redQ  = (float*)(ldsc + 2048);
    float* redS2 = (float*)(ldsc + 4096);
    float* redQ2 = (float*)(ldsc + 6144);
    int colbase = wc * 64 + (lane & 15);
    int qrow = (lane >> 4) << 2;
    float mgv[4], mbv[4], egv[4], ebv[4];
#pragma unroll
    for (int nt = 0; nt < 4; ++nt) {
        int c = colbase + nt * 16;
        mgv[nt] = mg[c]; mbv[nt] = mb[c]; egv[nt] = eg[c]; ebv[nt] = eb[c];
    }
#pragma unroll
    for (int mt = 0; mt < 2; ++mt)
#pragma unroll
        for (int r = 0; r < 4; ++r) {
            float s = 0.f, q = 0.f;
#pragma unroll
            for (int nt = 0; nt < 4; ++nt) {
                float v = acc[mt][nt][r];
                s += v; q += v * v;
            }
            s = red16(s); q = red16(q);
            if ((lane & 15) == 0) {
                int lr = wr * 32 + qrow + mt * 16 + r;
                redS[lr * 2 + wc] = s; redQ[lr * 2 + wc] = q;
            }
        }
    __syncthreads();
#pragma unroll
    for (int mt = 0; mt < 2; ++mt)
#pragma unroll
        for (int r = 0; r < 4; ++r) {
            int lr = wr * 32 + qrow + mt * 16 + r;
            float mu = (redS[lr * 2] + redS[lr * 2 + 1]) * (1.f / 128.f);
            float var = (redQ[lr * 2] + redQ[lr * 2 + 1]) * (1.f / 128.f) - mu * mu;
            float rs = rsqrtf(var + 1e-5f);
            size_t rbase = (size_t)(row0 + lr) * 128;
            float s2 = 0.f, q2 = 0.f;
#pragma unroll
            for (int nt = 0; nt < 4; ++nt) {
                float o = (acc[mt][nt][r] - mu) * rs * mgv[nt] + mbv[nt];
                float z = o + bf2f(h[rbase + colbase + nt * 16]);
                acc[mt][nt][r] = z;
                s2 += z; q2 += z * z;
            }
            s2 = red16(s2); q2 = red16(q2);
            if ((lane & 15) == 0) {
                redS2[lr * 2 + wc] = s2; redQ2[lr * 2 + wc] = q2;
            }
        }
    __syncthreads();
    int bb = row0 >> 8;
#pragma unroll
    for (int mt = 0; mt < 2; ++mt) {
        u16 tvals[4][4];   // [nt][r]
#pragma unroll
        for (int r = 0; r < 4; ++r) {
            int lr = wr * 32 + qrow + mt * 16 + r;
            float mu = (redS2[lr * 2] + redS2[lr * 2 + 1]) * (1.f / 128.f);
            float var = (redQ2[lr * 2] + redQ2[lr * 2 + 1]) * (1.f / 128.f) - mu * mu;
            float rs = rsqrtf(var + 1e-5f);
            size_t rbase = (size_t)(row0 + lr) * 128;
#pragma unroll
            for (int nt = 0; nt < 4; ++nt) {
                float z = acc[mt][nt][r];
                u16 o = f2bf((z - mu) * rs * egv[nt] + ebv[nt]);
                h[rbase + colbase + nt * 16] = o;
                tvals[nt][r] = o;
            }
        }
        int node0 = ((row0 & 255) + wr * 32 + qrow + mt * 16);
#pragma unroll
        for (int nt = 0; nt < 4; ++nt) {
            int d = colbase + nt * 16;
            *(ushort4*)(hT + (size_t)bb * 32768 + (size_t)d * 256 + node0) = *(ushort4*)tvals[nt];
        }
    }
}

// ---------------- fused attention: per (b, head, qhalf) block; packed Q/K/V; bf16 mat; P in registers ----------------
// grid (NB, 4, 2): 1024 blocks -> 2 scheduling rounds, staging overlaps compute across rounds.

__global__ __launch_bounds__(512) void attn_k(const u16* __restrict__ qP,
                                              const u16* __restrict__ kP,
                                              const u16* __restrict__ vT,
                                              const u16* __restrict__ matB,
                                              u16* __restrict__ ctx) {
    __shared__ __align__(16) u16 Kl[256 * 72];   // 36864 B (padded rows)
    __shared__ __align__(16) u16 Vl[64 * 264];   // 33792 B (padded rows)
    int t = threadIdx.x, lane = t & 63, w = t >> 6;
    int b = blockIdx.x, hh = blockIdx.y, zh = blockIdx.z;
    int bh = b * 4 + hh;
    int lg = lane >> 4, q16 = lane & 15;
    int qrow_l = zh * 128 + w * 16;

    // Q-fragment load hoisted above the barrier (global, independent of LDS staging)
    const u16* qsrc = qP + (size_t)bh * 16384 + (qrow_l + q16) * 64 + (lg << 3);
    bf16x8 aq0 = *(const bf16x8*)(qsrc);
    bf16x8 aq1 = *(const bf16x8*)(qsrc + 32);

    // --- staging from packed buffers (dense 32KB each), all 512 threads ---
    {
        const u16* kb = kP + (size_t)bh * 16384;
#pragma unroll
        for (int i = 0; i < 4; ++i) {
            int idx = i * 512 + t;              // 2048 x 16B; K row = 64 u16 = 8 chunks
            int node = idx >> 3, oct = idx & 7;
            *(uint4*)(Kl + node * 72 + oct * 8) = *(const uint4*)(kb + node * 64 + oct * 8);
        }
        const u16* vb = vT + (size_t)bh * 16384;
#pragma unroll
        for (int i = 0; i < 4; ++i) {
            int idx = i * 512 + t;              // 2048 x 16B; V row = 256 u16 = 32 chunks
            int d = idx >> 5, p = idx & 31;
            *(uint4*)(Vl + d * 264 + p * 8) = *(const uint4*)(vb + d * 256 + p * 8);
        }
    }
    __syncthreads();

    f32x4 zero = {0.f, 0.f, 0.f, 0.f};
    bool loA = (lg < 2);
    int s01 = q16 + ((lg & 1) << 5);
    int s23 = s01 + 16;

    f32x4 sc[16];
    __builtin_amdgcn_s_setprio(1);
#pragma unroll
    for (int nt = 0; nt < 16; ++nt) {
        const u16* ks = Kl + (nt * 16 + q16) * 72 + (lg << 3);
        bf16x8 k0 = *(const bf16x8*)(ks);
        bf16x8 k1 = *(const bf16x8*)(ks + 32);
        f32x4 a = __builtin_amdgcn_mfma_f32_16x16x32_bf16(k0, aq0, zero, 0, 0, 0);
        a = __builtin_amdgcn_mfma_f32_16x16x32_bf16(k1, aq1, a, 0, 0, 0);
        sc[nt] = a;
    }
    __builtin_amdgcn_s_setprio(0);

    const u16* mrow = matB + ((size_t)b * LL + qrow_l + q16) * LL + (lg << 2);
#pragma unroll
    for (int nt = 0; nt < 16; ++nt) {
        ushort4 mv = *(const ushort4*)(mrow + nt * 16);
        sc[nt][0] *= bf2f(mv.x);
        sc[nt][1] *= bf2f(mv.y);
        sc[nt][2] *= bf2f(mv.z);
        sc[nt][3] *= bf2f(mv.w);
    }

    float mx = -1e30f;
#pragma unroll
    for (int nt = 0; nt < 16; ++nt)
#pragma unroll
        for (int r = 0; r < 4; ++r) mx = fmaxf(mx, sc[nt][r]);
    mx = fmaxf(mx, __shfl_xor(mx, 16, 64));
    mx = fmaxf(mx, __shfl_xor(mx, 32, 64));
    float sm = 0.f;
#pragma unroll
    for (int nt = 0; nt < 16; ++nt)
#pragma unroll
        for (int r = 0; r < 4; ++r) {
            float e = __expf(sc[nt][r] - mx);
            sc[nt][r] = e;
            sm += e;
        }
    sm += __shfl_xor(sm, 16, 64);
    sm += __shfl_xor(sm, 32, 64);
    float inv = 1.f / sm;
#pragma unroll
    for (int nt = 0; nt < 16; ++nt)
#pragma unroll
        for (int r = 0; r < 4; ++r) sc[nt][r] *= inv;

    f32x4 oa[4];
#pragma unroll
    for (int dt = 0; dt < 4; ++dt) oa[dt] = zero;
    __builtin_amdgcn_s_setprio(1);
#pragma unroll
    for (int kt = 0; kt < 8; ++kt) {
        u32 A0 = cvtpk(sc[2 * kt][0], sc[2 * kt][1]);
        u32 A1 = cvtpk(sc[2 * kt][2], sc[2 * kt][3]);
        u32 B0 = cvtpk(sc[2 * kt + 1][0], sc[2 * kt + 1][1]);
        u32 B1 = cvtpk(sc[2 * kt + 1][2], sc[2 * kt + 1][3]);
        u32 a0s = bperm(s01, A0), b0s = bperm(s01, B0);
        u32 a1s = bperm(s01, A1), b1s = bperm(s01, B1);
        u32 a0t = bperm(s23, A0), b0t = bperm(s23, B0);
        u32 a1t = bperm(s23, A1), b1t = bperm(s23, B1);
        union { u32 u[4]; bf16x8 v; } pa;
        pa.u[0] = loA ? a0s : b0s;
        pa.u[1] = loA ? a1s : b1s;
        pa.u[2] = loA ? a0t : b0t;
        pa.u[3] = loA ? a1t : b1t;
#pragma unroll
        for (int dt = 0; dt < 4; ++dt) {
            bf16x8 bv = *(const bf16x8*)(Vl + (dt * 16 + q16) * 264 + kt * 32 + (lg << 3));
            oa[dt] = __builtin_amdgcn_mfma_f32_16x16x32_bf16(pa.v, bv, oa[dt], 0, 0, 0);
        }
    }
    __builtin_amdgcn_s_setprio(0);
#pragma unroll
    for (int dt = 0; dt < 4; ++dt)
#pragma unroll
        for (int r = 0; r < 4; ++r)
            ctx[(size_t)(b * LL + qrow_l + (lg << 2) + r) * 256 + hh * 64 + dt * 16 + q16] = f2bf(oa[dt][r]);
}

// ---------------- host launch ----------------

extern "C" void kernel_launch(void* const* d_in, const int* in_sizes, int n_in,
                              void* d_out, int out_size, void* d_ws, size_t ws_size,
                              hipStream_t stream) {
    (void)out_size; (void)ws_size; (void)n_in;
    const float* x        = (const float*)d_in[0];
    const int*   ei       = (const int*)d_in[1];
    const float* ea       = (const float*)d_in[2];
    const float* adj      = (const float*)d_in[3];
    const float* dis      = (const float*)d_in[4];
    int pb = (in_sizes[5] == 5120) ? 5 : 6;
    const float* g0_rel_w = (const float*)d_in[pb + 0];
    const float* g0_rel_b = (const float*)d_in[pb + 1];
    const float* g0_root_w= (const float*)d_in[pb + 2];
    const float* g_rel_w  = (const float*)d_in[pb + 3];
    const float* g_rel_b  = (const float*)d_in[pb + 4];
    const float* g_root_w = (const float*)d_in[pb + 5];
    const float* nm_g     = (const float*)d_in[pb + 6];
    const float* nm_b     = (const float*)d_in[pb + 7];
    const float* wq       = (const float*)d_in[pb + 8];
    const float* wk       = (const float*)d_in[pb + 9];
    const float* wv       = (const float*)d_in[pb + 10];
    const float* fc       = (const float*)d_in[pb + 11];
    const float* mha_g    = (const float*)d_in[pb + 12];
    const float* mha_b    = (const float*)d_in[pb + 13];
    const float* enc_g    = (const float*)d_in[pb + 14];
    const float* enc_b    = (const float*)d_in[pb + 15];
    const float* proj_w   = (const float*)d_in[pb + 16];
    const float* proj_b   = (const float*)d_in[pb + 17];
    const int* srcI = ei;
    const int* dstI = ei + EDGES;

    char* w = (char*)d_ws;
    float* Wf     = (float*)w; w += (size_t)33554432;   // W f32 scatter, then reused as matB (bf16)
    u16*   ctx    = (u16*)w;   w += (size_t)16777216;   // attn output [N,256]
    u16*   h      = (u16*)w;   w += (size_t)8388608;
    u16*   qP     = (u16*)w;   w += (size_t)16777216;   // packed Q [bh][256][64]
    u16*   kP     = (u16*)w;   w += (size_t)16777216;   // packed K [bh][256][64]
    u16*   Wb     = (u16*)w;   w += (size_t)16777216;   // W bf16 [128][256][256]
    u16*   bigT   = (u16*)w;   w += (size_t)16777216;   // hT (8.4MB) / vT (16.7MB), time-disjoint
    u16* wconvT0  = (u16*)w;   w += (size_t)32768;
    u16* wconvT   = (u16*)w;   w += (size_t)196608;
    u16* wqkvT    = (u16*)w;   w += (size_t)786432;
    u16* fcT      = (u16*)w;   w += (size_t)262144;
    u16* projT    = (u16*)w;   w += (size_t)32768;
    u16*   matB = (u16*)Wf;
    u16*   hT  = bigT;
    u16*   vT  = bigT;

    // --- prep (cast MUST precede build_matrix: matB aliases Wf) ---
    zero_wf_k<<<8192, 256, 0, stream>>>((float4*)Wf);
    scatter_w_k<<<2048, 256, 0, stream>>>(srcI, dstI, ea, Wf);
    cast_w_k<<<8192, 256, 0, stream>>>(Wf, Wb);
    build_matrix_k<<<32768, 256, 0, stream>>>(adj, dis, matB);
    prep_weights_k<<<2560, 256, 0, stream>>>(g0_rel_w, g0_root_w, g_rel_w, g_root_w,
                                             wq, wk, wv, fc, proj_w,
                                             wconvT0, wconvT, wqkvT, fcT, projT);
    transpose_x_k<<<2048, 256, 0, stream>>>(x, hT);

    for (int L = 0; L < 4; ++L) {
        if (L == 0)
            gemm_agg_conv<true><<<256, 512, 0, stream>>>(Wb, hT, x, h, wconvT0,
                                                         g0_rel_b, nm_g, nm_b);
        else
            gemm_agg_conv<false><<<256, 512, 0, stream>>>(Wb, hT, x, h, wconvT + (L - 1) * 32768,
                                                          g_rel_b + (L - 1) * 128,
                                                          nm_g + L * 128, nm_b + L * 128);
        gemm_qkv<<<dim3(256, 6), 256, 0, stream>>>(h, wqkvT + L * 98304, qP, kP, vT);
        attn_k<<<dim3(NB, 4, 2), 512, 0, stream>>>(qP, kP, vT, matB, ctx);
        gemm_fc_ln2<<<256, 512, 0, stream>>>(ctx, fcT + L * 32768,
                                             mha_g + L * 128, mha_b + L * 128,
                                             enc_g + L * 128, enc_b + L * 128, h, hT);
    }
    gemm_proj<<<256, 256, 0, stream>>>(h, projT, (float*)d_out, proj_b);
}